// Round 1
// baseline (705.089 us; speedup 1.0000x reference)
//
#include <hip/hip_runtime.h>
#include <hip/hip_bf16.h>
#include <math.h>

typedef __attribute__((ext_vector_type(4))) float f32x4;
typedef __attribute__((ext_vector_type(8))) short short8;

#define NBINS 1000
#define LDK 40  // padded LDS row stride in shorts (32 data + 8 pad)

__device__ __forceinline__ unsigned short f2bf(float x) {
  union { float f; unsigned u; } c; c.f = x;
  unsigned u = c.u;
  unsigned r = (u + 0x7FFFu + ((u >> 16) & 1u)) >> 16;  // RNE
  return (unsigned short)r;
}
__device__ __forceinline__ float bf2f(unsigned short h) {
  union { unsigned u; float f; } c; c.u = ((unsigned)h) << 16;
  return c.f;
}

// ---------------------------------------------------------------------------
// prep: round z to bf16 (stored for the GEMM) and compute row norms from the
// ROUNDED values (self-consistent with the MFMA dot products).
// grid: (2*B)/4 blocks of 256; one 64-lane wave per row.
// ---------------------------------------------------------------------------
__global__ __launch_bounds__(256)
void prep_kernel(const float* __restrict__ za, const float* __restrict__ zb,
                 float* __restrict__ na, float* __restrict__ nb,
                 unsigned short* __restrict__ zba, unsigned short* __restrict__ zbb,
                 int B, int D)
{
  const int row = blockIdx.x * 4 + (threadIdx.x >> 6);
  const int lane = threadIdx.x & 63;
  const float* src; float* dst; unsigned short* bd; int r;
  if (row < B) { src = za; dst = na; bd = zba; r = row; }
  else         { src = zb; dst = nb; bd = zbb; r = row - B; }
  float s = 0.f;
  for (int c = lane * 4; c < D; c += 256) {
    const f32x4 v = *(const f32x4*)&src[(size_t)r * D + c];
    unsigned short h0 = f2bf(v[0]), h1 = f2bf(v[1]), h2 = f2bf(v[2]), h3 = f2bf(v[3]);
    union { unsigned short us[4]; uint2 u2; } pk;
    pk.us[0] = h0; pk.us[1] = h1; pk.us[2] = h2; pk.us[3] = h3;
    *(uint2*)&bd[(size_t)r * D + c] = pk.u2;
    const float x0 = bf2f(h0), x1 = bf2f(h1), x2 = bf2f(h2), x3 = bf2f(h3);
    s += x0 * x0 + x1 * x1 + x2 * x2 + x3 * x3;
  }
#pragma unroll
  for (int off = 32; off; off >>= 1) s += __shfl_xor(s, off);
  if (lane == 0) dst[r] = s;
}

// ---------------------------------------------------------------------------
// Efron Cox loss via integer-time binning. One block per loss (grid=2).
// ---------------------------------------------------------------------------
__global__ __launch_bounds__(1024)
void cox_kernel(const float* __restrict__ r0, const int* __restrict__ e0, const int* __restrict__ t0,
                const float* __restrict__ r1, const int* __restrict__ e1, const int* __restrict__ t1,
                float* __restrict__ out, int B)
{
  const int bid = blockIdx.x;
  const float* risk = bid ? r1 : r0;
  const int* evt = bid ? e1 : e0;
  const int* tm  = bid ? t1 : t0;
  const int tid = threadIdx.x;
  const int NT = 1024;

  __shared__ float sS[NBINS], sT[NBINS], sDc[NBINS];
  __shared__ float sc0[NBINS], sc1[NBINS];
  __shared__ float red[16];
  __shared__ float red3[48];

  // global max of risk
  float m = -3.0e38f;
  for (int i = tid; i < B; i += NT) m = fmaxf(m, risk[i]);
#pragma unroll
  for (int off = 32; off; off >>= 1) m = fmaxf(m, __shfl_xor(m, off));
  if ((tid & 63) == 0) red[tid >> 6] = m;
  __syncthreads();
  if (tid == 0) {
    float mm = red[0];
    for (int wv = 1; wv < 16; ++wv) mm = fmaxf(mm, red[wv]);
    red[0] = mm;
  }
  __syncthreads();
  const float maxr = red[0];

  for (int i = tid; i < NBINS; i += NT) { sS[i] = 0.f; sT[i] = 0.f; sDc[i] = 0.f; }
  __syncthreads();

  // per-bin accumulation
  float sr = 0.f, nev = 0.f;
  for (int i = tid; i < B; i += NT) {
    const float r = risk[i];
    int t = tm[i];
    t = t < 0 ? 0 : (t >= NBINS ? NBINS - 1 : t);
    const float ex = expf(r - maxr);
    atomicAdd(&sS[t], ex);
    if (evt[i]) {
      atomicAdd(&sT[t], ex);
      atomicAdd(&sDc[t], 1.0f);
      sr += r; nev += 1.0f;
    }
  }
  __syncthreads();

  // suffix sum over bins: rss[t] = sum_{t' >= t} S[t']
  for (int i = tid; i < NBINS; i += NT) sc0[i] = sS[i];
  __syncthreads();
  float* pin = sc0; float* pout = sc1;
  for (int off = 1; off < NBINS; off <<= 1) {
    for (int i = tid; i < NBINS; i += NT) {
      float v = pin[i];
      if (i + off < NBINS) v += pin[i + off];
      pout[i] = v;
    }
    __syncthreads();
    float* tmp = pin; pin = pout; pout = tmp;
  }

  // Efron per-bin log terms
  float ls = 0.f;
  for (int t = tid; t < NBINS; t += NT) {
    const float d = sDc[t];
    if (d > 0.f) {
      const float tes = sT[t];
      const float rs = pin[t];
      for (float l = 0.f; l < d - 0.5f; l += 1.f)
        ls += logf(rs - (l / d) * tes + 1e-12f);
    }
  }

  float v1 = sr, v2 = nev, v3 = ls;
#pragma unroll
  for (int off = 32; off; off >>= 1) {
    v1 += __shfl_xor(v1, off); v2 += __shfl_xor(v2, off); v3 += __shfl_xor(v3, off);
  }
  if ((tid & 63) == 0) { int wv = tid >> 6; red3[wv] = v1; red3[16 + wv] = v2; red3[32 + wv] = v3; }
  __syncthreads();
  if (tid == 0) {
    float SR = 0.f, NEV = 0.f, LS = 0.f;
    for (int wv = 0; wv < 16; ++wv) { SR += red3[wv]; NEV += red3[16 + wv]; LS += red3[32 + wv]; }
    out[bid] = -(SR - LS - NEV * maxr) / (NEV + 1e-12f);
  }
}

// ---------------------------------------------------------------------------
// Fused double-Gram distance-correlation statistics.
// 128x128 output tile per block, 4 waves (2x2), 16x16x32 bf16 MFMA.
// Accumulates: scal[0]=Sum Da*Db, scal[1]=Sum Da^2, scal[2]=Sum Db^2 (double),
// Ra[i]/Rb[i] row sums (float atomics).
// ---------------------------------------------------------------------------
__global__ __launch_bounds__(256, 2)
void dcor_kernel(const unsigned short* __restrict__ zba,
                 const unsigned short* __restrict__ zbb,
                 const float* __restrict__ na, const float* __restrict__ nb,
                 float* __restrict__ Ra, float* __restrict__ Rb,
                 double* __restrict__ scal, int B, int D)
{
  __shared__ __align__(16) unsigned short sAi[128 * LDK];
  __shared__ __align__(16) unsigned short sAj[128 * LDK];
  __shared__ __align__(16) unsigned short sBi[128 * LDK];
  __shared__ __align__(16) unsigned short sBj[128 * LDK];

  const int tid = threadIdx.x;
  const int ntile = B >> 7;
  const int ib = blockIdx.x / ntile;
  const int jb = blockIdx.x % ntile;
  const int lane = tid & 63;
  const int wid = tid >> 6;
  const int wr = wid >> 1;
  const int wc = wid & 1;
  const int lrow = lane & 15;
  const int kg = lane >> 4;

  const size_t rowi = (size_t)ib * 128;
  const size_t rowj = (size_t)jb * 128;

  const f32x4 Z4 = {0.f, 0.f, 0.f, 0.f};
  f32x4 accA[4][4], accB[4][4];
#pragma unroll
  for (int m = 0; m < 4; ++m)
#pragma unroll
    for (int n = 0; n < 4; ++n) { accA[m][n] = Z4; accB[m][n] = Z4; }

  const int sr_row = tid >> 2;       // 0..63
  const int sr_c8 = (tid & 3) * 8;   // short offset within 32-col slice

  for (int kk = 0; kk < D; kk += 32) {
#pragma unroll
    for (int p = 0; p < 2; ++p) {
      const int r = p * 64 + sr_row;
      const size_t off_i = (rowi + r) * (size_t)D + kk + sr_c8;
      const size_t off_j = (rowj + r) * (size_t)D + kk + sr_c8;
      const int lo = r * LDK + sr_c8;
      *(uint4*)&sAi[lo] = *(const uint4*)&zba[off_i];
      *(uint4*)&sAj[lo] = *(const uint4*)&zba[off_j];
      *(uint4*)&sBi[lo] = *(const uint4*)&zbb[off_i];
      *(uint4*)&sBj[lo] = *(const uint4*)&zbb[off_j];
    }
    __syncthreads();

    short8 aA[4], bA[4], aB[4], bB[4];
#pragma unroll
    for (int m2 = 0; m2 < 4; ++m2) {
      const int ri = (wr * 64 + m2 * 16 + lrow) * LDK + kg * 8;
      const int rj = (wc * 64 + m2 * 16 + lrow) * LDK + kg * 8;
      aA[m2] = *(const short8*)&sAi[ri];
      bA[m2] = *(const short8*)&sAj[rj];
      aB[m2] = *(const short8*)&sBi[ri];
      bB[m2] = *(const short8*)&sBj[rj];
    }
#pragma unroll
    for (int m2 = 0; m2 < 4; ++m2)
#pragma unroll
      for (int n2 = 0; n2 < 4; ++n2) {
        accA[m2][n2] = __builtin_amdgcn_mfma_f32_16x16x32_bf16(aA[m2], bA[n2], accA[m2][n2], 0, 0, 0);
        accB[m2][n2] = __builtin_amdgcn_mfma_f32_16x16x32_bf16(aB[m2], bB[n2], accB[m2][n2], 0, 0, 0);
      }
    __syncthreads();
  }

  // Epilogue: D entries, scalar sums, row sums.
  // C/D layout (16x16x32): col = lane&15, row = (lane>>4)*4 + reg.
  float pab = 0.f, paa = 0.f, pbb = 0.f;
  float rsa[4][4], rsb[4][4];
#pragma unroll
  for (int m2 = 0; m2 < 4; ++m2)
#pragma unroll
    for (int r = 0; r < 4; ++r) { rsa[m2][r] = 0.f; rsb[m2][r] = 0.f; }

  const int gi0 = ib * 128 + wr * 64;
  const int gj0 = jb * 128 + wc * 64;

#pragma unroll
  for (int m2 = 0; m2 < 4; ++m2) {
    const int gr = gi0 + m2 * 16 + kg * 4;
    const f32x4 nai = *(const f32x4*)&na[gr];
    const f32x4 nbi = *(const f32x4*)&nb[gr];
#pragma unroll
    for (int n2 = 0; n2 < 4; ++n2) {
      const int gc = gj0 + n2 * 16 + lrow;
      const float naj = na[gc];
      const float nbj = nb[gc];
      const f32x4 ga = accA[m2][n2];
      const f32x4 gb = accB[m2][n2];
#pragma unroll
      for (int r = 0; r < 4; ++r) {
        const float d2a = fmaxf(nai[r] + naj - 2.0f * ga[r], 1e-8f);
        const float d2b = fmaxf(nbi[r] + nbj - 2.0f * gb[r], 1e-8f);
        const float Da = sqrtf(d2a);
        const float Db = sqrtf(d2b);
        pab += Da * Db;
        paa += d2a;        // Da*Da == clamped d2a exactly
        pbb += d2b;
        rsa[m2][r] += Da;
        rsb[m2][r] += Db;
      }
    }
  }

  // row-sum partials: reduce across the 16 lanes sharing a row set (lrow axis)
#pragma unroll
  for (int m2 = 0; m2 < 4; ++m2)
#pragma unroll
    for (int r = 0; r < 4; ++r) {
      float va = rsa[m2][r], vb = rsb[m2][r];
      va += __shfl_xor(va, 1); va += __shfl_xor(va, 2); va += __shfl_xor(va, 4); va += __shfl_xor(va, 8);
      vb += __shfl_xor(vb, 1); vb += __shfl_xor(vb, 2); vb += __shfl_xor(vb, 4); vb += __shfl_xor(vb, 8);
      if (lrow == 0) {
        const int gi = gi0 + m2 * 16 + kg * 4 + r;
        atomicAdd(&Ra[gi], va);
        atomicAdd(&Rb[gi], vb);
      }
    }

  float t1 = pab, t2 = paa, t3 = pbb;
#pragma unroll
  for (int off = 32; off; off >>= 1) {
    t1 += __shfl_xor(t1, off); t2 += __shfl_xor(t2, off); t3 += __shfl_xor(t3, off);
  }
  if (lane == 0) {
    atomicAdd(&scal[0], (double)t1);
    atomicAdd(&scal[1], (double)t2);
    atomicAdd(&scal[2], (double)t3);
  }
}

// ---------------------------------------------------------------------------
// Final combine (fp64 to survive the ~4-decade cancellation in S terms).
// ---------------------------------------------------------------------------
__global__ __launch_bounds__(256)
void finalize_kernel(const float* __restrict__ Ra, const float* __restrict__ Rb,
                     const double* __restrict__ scal, const float* __restrict__ coxo,
                     const float* __restrict__ iw, const float* __restrict__ ic,
                     float* __restrict__ out, int B)
{
  const int tid = threadIdx.x;
  double ta = 0, tb = 0, sab = 0, saa = 0, sbb = 0;
  for (int i = tid; i < B; i += 256) {
    const double a = Ra[i], b = Rb[i];
    ta += a; tb += b; sab += a * b; saa += a * a; sbb += b * b;
  }
#pragma unroll
  for (int off = 32; off; off >>= 1) {
    ta += __shfl_xor(ta, off); tb += __shfl_xor(tb, off);
    sab += __shfl_xor(sab, off); saa += __shfl_xor(saa, off); sbb += __shfl_xor(sbb, off);
  }
  __shared__ double sred[20];
  const int w = tid >> 6;
  if ((tid & 63) == 0) {
    sred[w] = ta; sred[4 + w] = tb; sred[8 + w] = sab; sred[12 + w] = saa; sred[16 + w] = sbb;
  }
  __syncthreads();
  if (tid == 0) {
    ta = sred[0] + sred[1] + sred[2] + sred[3];
    tb = sred[4] + sred[5] + sred[6] + sred[7];
    sab = sred[8] + sred[9] + sred[10] + sred[11];
    saa = sred[12] + sred[13] + sred[14] + sred[15];
    sbb = sred[16] + sred[17] + sred[18] + sred[19];
    const double n = (double)B;
    const double Pab = scal[0], Paa = scal[1], Pbb = scal[2];
    const double Sab = Pab - (2.0 / n) * sab + ta * tb / (n * n);
    const double Saa = Paa - (2.0 / n) * saa + ta * ta / (n * n);
    const double Sbb = Pbb - (2.0 / n) * sbb + tb * tb / (n * n);
    const double dcov = Sab / (n * n);
    const double va = Saa / (n * n);
    const double vb = Sbb / (n * n);
    const double l_cca = 1.0 - dcov / sqrt(fmax(va * vb, 1e-8));
    const double total = (double)coxo[0] + (double)coxo[1]
                       + (0.1 * l_cca + 0.05 * ((double)iw[0] + (double)ic[0]));
    out[0] = (float)total;
  }
}

// ---------------------------------------------------------------------------
extern "C" void kernel_launch(void* const* d_in, const int* in_sizes, int n_in,
                              void* d_out, int out_size, void* d_ws, size_t ws_size,
                              hipStream_t stream)
{
  (void)n_in; (void)out_size; (void)ws_size;
  const float* risk_os   = (const float*)d_in[0];
  const float* risk_rfs  = (const float*)d_in[1];
  const float* z_ct      = (const float*)d_in[2];
  const float* z_wsi     = (const float*)d_in[3];
  const float* intra_wsi = (const float*)d_in[4];
  const float* intra_ct  = (const float*)d_in[5];
  const int* evt_os  = (const int*)d_in[6];
  const int* tm_os   = (const int*)d_in[7];
  const int* evt_rfs = (const int*)d_in[8];
  const int* tm_rfs  = (const int*)d_in[9];

  const int B = in_sizes[0];        // 8192
  const int D = in_sizes[2] / B;    // 256

  // ws layout (float units):
  // [0,B) Ra | [B,2B) Rb | [2B,2B+8) scal (4 doubles) | [2B+8,2B+10) cox |
  // [2B+16,3B+16) na | [3B+16,4B+16) nb | then bf16 copies of z_ct, z_wsi
  float* ws = (float*)d_ws;
  float* Ra = ws;
  float* Rb = ws + B;
  double* scal = (double*)(ws + 2 * B);
  float* coxo = ws + 2 * B + 8;
  float* na  = ws + 2 * B + 16;
  float* nbv = ws + 3 * B + 16;
  unsigned short* zba = (unsigned short*)(ws + 4 * B + 16);
  unsigned short* zbb = zba + (size_t)B * D;

  hipMemsetAsync(d_ws, 0, (size_t)(2 * B + 8) * sizeof(float), stream);

  prep_kernel<<<(2 * B) / 4, 256, 0, stream>>>(z_ct, z_wsi, na, nbv, zba, zbb, B, D);
  cox_kernel<<<2, 1024, 0, stream>>>(risk_os, evt_os, tm_os, risk_rfs, evt_rfs, tm_rfs, coxo, B);
  const int nt = B / 128;
  dcor_kernel<<<nt * nt, 256, 0, stream>>>(zba, zbb, na, nbv, Ra, Rb, scal, B, D);
  finalize_kernel<<<1, 256, 0, stream>>>(Ra, Rb, scal, coxo, intra_wsi, intra_ct, (float*)d_out, B);
}

// Round 2
// 243.189 us; speedup vs baseline: 2.8993x; 2.8993x over previous
//
#include <hip/hip_runtime.h>
#include <hip/hip_bf16.h>
#include <math.h>

typedef __attribute__((ext_vector_type(4))) float f32x4;
typedef __attribute__((ext_vector_type(8))) short short8;

#define NBINS 1000

__device__ __forceinline__ unsigned short f2bf(float x) {
  union { float f; unsigned u; } c; c.f = x;
  unsigned u = c.u;
  unsigned r = (u + 0x7FFFu + ((u >> 16) & 1u)) >> 16;  // RNE
  return (unsigned short)r;
}
__device__ __forceinline__ float bf2f(unsigned short h) {
  union { unsigned u; float f; } c; c.u = ((unsigned)h) << 16;
  return c.f;
}

// direct global -> LDS async copy, 16B per lane; LDS dest is wave-uniform base
__device__ __forceinline__ void gl16(const void* g, void* l) {
  __builtin_amdgcn_global_load_lds(
      (const __attribute__((address_space(1))) unsigned int*)g,
      (__attribute__((address_space(3))) unsigned int*)l, 16, 0, 0);
}

// ---------------------------------------------------------------------------
// prep: round z to bf16 (stored for the GEMM) and compute row norms from the
// ROUNDED values (self-consistent with the MFMA dot products).
// ---------------------------------------------------------------------------
__global__ __launch_bounds__(256)
void prep_kernel(const float* __restrict__ za, const float* __restrict__ zb,
                 float* __restrict__ na, float* __restrict__ nb,
                 unsigned short* __restrict__ zba, unsigned short* __restrict__ zbb,
                 int B, int D)
{
  const int row = blockIdx.x * 4 + (threadIdx.x >> 6);
  const int lane = threadIdx.x & 63;
  const float* src; float* dst; unsigned short* bd; int r;
  if (row < B) { src = za; dst = na; bd = zba; r = row; }
  else         { src = zb; dst = nb; bd = zbb; r = row - B; }
  float s = 0.f;
  for (int c = lane * 4; c < D; c += 256) {
    const f32x4 v = *(const f32x4*)&src[(size_t)r * D + c];
    unsigned short h0 = f2bf(v[0]), h1 = f2bf(v[1]), h2 = f2bf(v[2]), h3 = f2bf(v[3]);
    union { unsigned short us[4]; uint2 u2; } pk;
    pk.us[0] = h0; pk.us[1] = h1; pk.us[2] = h2; pk.us[3] = h3;
    *(uint2*)&bd[(size_t)r * D + c] = pk.u2;
    const float x0 = bf2f(h0), x1 = bf2f(h1), x2 = bf2f(h2), x3 = bf2f(h3);
    s += x0 * x0 + x1 * x1 + x2 * x2 + x3 * x3;
  }
#pragma unroll
  for (int off = 32; off; off >>= 1) s += __shfl_xor(s, off);
  if (lane == 0) dst[r] = s;
}

// ---------------------------------------------------------------------------
// Efron Cox loss via integer-time binning. One block per loss (grid=2).
// ---------------------------------------------------------------------------
__global__ __launch_bounds__(1024)
void cox_kernel(const float* __restrict__ r0, const int* __restrict__ e0, const int* __restrict__ t0,
                const float* __restrict__ r1, const int* __restrict__ e1, const int* __restrict__ t1,
                float* __restrict__ out, int B)
{
  const int bid = blockIdx.x;
  const float* risk = bid ? r1 : r0;
  const int* evt = bid ? e1 : e0;
  const int* tm  = bid ? t1 : t0;
  const int tid = threadIdx.x;
  const int NT = 1024;

  __shared__ float sS[NBINS], sT[NBINS], sDc[NBINS];
  __shared__ float sc0[NBINS], sc1[NBINS];
  __shared__ float red[16];
  __shared__ float red3[48];

  float m = -3.0e38f;
  for (int i = tid; i < B; i += NT) m = fmaxf(m, risk[i]);
#pragma unroll
  for (int off = 32; off; off >>= 1) m = fmaxf(m, __shfl_xor(m, off));
  if ((tid & 63) == 0) red[tid >> 6] = m;
  __syncthreads();
  if (tid == 0) {
    float mm = red[0];
    for (int wv = 1; wv < 16; ++wv) mm = fmaxf(mm, red[wv]);
    red[0] = mm;
  }
  __syncthreads();
  const float maxr = red[0];

  for (int i = tid; i < NBINS; i += NT) { sS[i] = 0.f; sT[i] = 0.f; sDc[i] = 0.f; }
  __syncthreads();

  float sr = 0.f, nev = 0.f;
  for (int i = tid; i < B; i += NT) {
    const float r = risk[i];
    int t = tm[i];
    t = t < 0 ? 0 : (t >= NBINS ? NBINS - 1 : t);
    const float ex = expf(r - maxr);
    atomicAdd(&sS[t], ex);
    if (evt[i]) {
      atomicAdd(&sT[t], ex);
      atomicAdd(&sDc[t], 1.0f);
      sr += r; nev += 1.0f;
    }
  }
  __syncthreads();

  for (int i = tid; i < NBINS; i += NT) sc0[i] = sS[i];
  __syncthreads();
  float* pin = sc0; float* pout = sc1;
  for (int off = 1; off < NBINS; off <<= 1) {
    for (int i = tid; i < NBINS; i += NT) {
      float v = pin[i];
      if (i + off < NBINS) v += pin[i + off];
      pout[i] = v;
    }
    __syncthreads();
    float* tmp = pin; pin = pout; pout = tmp;
  }

  float ls = 0.f;
  for (int t = tid; t < NBINS; t += NT) {
    const float d = sDc[t];
    if (d > 0.f) {
      const float tes = sT[t];
      const float rs = pin[t];
      for (float l = 0.f; l < d - 0.5f; l += 1.f)
        ls += logf(rs - (l / d) * tes + 1e-12f);
    }
  }

  float v1 = sr, v2 = nev, v3 = ls;
#pragma unroll
  for (int off = 32; off; off >>= 1) {
    v1 += __shfl_xor(v1, off); v2 += __shfl_xor(v2, off); v3 += __shfl_xor(v3, off);
  }
  if ((tid & 63) == 0) { int wv = tid >> 6; red3[wv] = v1; red3[16 + wv] = v2; red3[32 + wv] = v3; }
  __syncthreads();
  if (tid == 0) {
    float SR = 0.f, NEV = 0.f, LS = 0.f;
    for (int wv = 0; wv < 16; ++wv) { SR += red3[wv]; NEV += red3[16 + wv]; LS += red3[32 + wv]; }
    out[bid] = -(SR - LS - NEV * maxr) / (NEV + 1e-12f);
  }
}

// ---------------------------------------------------------------------------
// Fused double-Gram distance-correlation statistics, symmetric (jb >= ib).
// 128x128 tile, 4 waves (2x2), 16x16x32 bf16 MFMA, global_load_lds + double
// buffer + source-side XOR swizzle (chunk ^= (row>>1)&3, involution).
// ---------------------------------------------------------------------------
__global__ __launch_bounds__(256)
void dcor_kernel(const unsigned short* __restrict__ zba,
                 const unsigned short* __restrict__ zbb,
                 const float* __restrict__ na, const float* __restrict__ nb,
                 float* __restrict__ Ra, float* __restrict__ Rb,
                 double* __restrict__ scalPart, int T, int nt, int B, int D)
{
  __shared__ __align__(16) short sAi[2][4096];
  __shared__ __align__(16) short sAj[2][4096];
  __shared__ __align__(16) short sBi[2][4096];
  __shared__ __align__(16) short sBj[2][4096];
  __shared__ double swred[12];

  const int tid = threadIdx.x;
  const int lane = tid & 63;
  const int w = tid >> 6;

  // triangular decode with XCD swizzle (T % 8 == 0 for B=8192)
  const int bid = blockIdx.x;
  const int idx = ((T & 7) == 0) ? ((bid & 7) * (T >> 3) + (bid >> 3)) : bid;
  const double tn = (double)(2 * nt + 1);
  int ib = (int)((tn - sqrt(tn * tn - 8.0 * (double)idx)) * 0.5);
  if (ib < 0) ib = 0;
  if (ib > nt - 1) ib = nt - 1;
  while (((ib + 1) * nt - ((ib + 1) * ib) / 2) <= idx) ++ib;
  while ((ib * nt - (ib * (ib - 1)) / 2) > idx) --ib;
  const int jb = ib + (idx - (ib * nt - (ib * (ib - 1)) / 2));
  const bool offd = (jb != ib);

  // staging geometry: lane covers LDS row (q*64 + w*16 + lane/4), 16B chunk lane%4
  const int l2 = lane >> 2;
  const int hs = (lane >> 3) & 3;              // (row>>1)&3 at stage time
  const int chunk = (lane & 3) ^ hs;           // inverse-swizzled source chunk
  const size_t rowi = (size_t)ib * 128;
  const size_t rowj = (size_t)jb * 128;
  const size_t gi_q0 = (rowi + w * 16 + l2) * (size_t)D + chunk * 8;
  const size_t gi_q1 = (rowi + 64 + w * 16 + l2) * (size_t)D + chunk * 8;
  const size_t gj_q0 = (rowj + w * 16 + l2) * (size_t)D + chunk * 8;
  const size_t gj_q1 = (rowj + 64 + w * 16 + l2) * (size_t)D + chunk * 8;
  const int wq0 = w * 512;
  const int wq1 = 2048 + w * 512;

#define STAGE(b, kks)                                   \
  do {                                                  \
    gl16(zba + gi_q0 + (kks), &sAi[b][wq0]);            \
    gl16(zba + gi_q1 + (kks), &sAi[b][wq1]);            \
    gl16(zba + gj_q0 + (kks), &sAj[b][wq0]);            \
    gl16(zba + gj_q1 + (kks), &sAj[b][wq1]);            \
    gl16(zbb + gi_q0 + (kks), &sBi[b][wq0]);            \
    gl16(zbb + gi_q1 + (kks), &sBi[b][wq1]);            \
    gl16(zbb + gj_q0 + (kks), &sBj[b][wq0]);            \
    gl16(zbb + gj_q1 + (kks), &sBj[b][wq1]);            \
  } while (0)

  // fragment geometry
  const int wr = w >> 1, wc = w & 1;
  const int lrow = lane & 15;
  const int kg = lane >> 4;
  const int hr = (lrow >> 1) & 3;              // (row>>1)&3 at read time
  const int roff = lrow * 32 + ((kg ^ hr) << 3);
  const int aoff = wr * 2048;
  const int boff = wc * 2048;

  const f32x4 Z4 = {0.f, 0.f, 0.f, 0.f};
  f32x4 accA[4][4], accB[4][4];
#pragma unroll
  for (int m = 0; m < 4; ++m)
#pragma unroll
    for (int n = 0; n < 4; ++n) { accA[m][n] = Z4; accB[m][n] = Z4; }

  int buf = 0;
  STAGE(0, 0);
  __syncthreads();

  const int nk = D >> 5;  // 8
  for (int t = 0; t < nk; ++t) {
    if (t + 1 < nk) { const int nb2 = buf ^ 1; STAGE(nb2, (size_t)((t + 1) * 32)); }
    {
      short8 aA[4], bA[4];
#pragma unroll
      for (int m2 = 0; m2 < 4; ++m2) {
        aA[m2] = *(const short8*)&sAi[buf][aoff + m2 * 512 + roff];
        bA[m2] = *(const short8*)&sAj[buf][boff + m2 * 512 + roff];
      }
#pragma unroll
      for (int m2 = 0; m2 < 4; ++m2)
#pragma unroll
        for (int n2 = 0; n2 < 4; ++n2)
          accA[m2][n2] = __builtin_amdgcn_mfma_f32_16x16x32_bf16(aA[m2], bA[n2], accA[m2][n2], 0, 0, 0);
    }
    {
      short8 aB[4], bB[4];
#pragma unroll
      for (int m2 = 0; m2 < 4; ++m2) {
        aB[m2] = *(const short8*)&sBi[buf][aoff + m2 * 512 + roff];
        bB[m2] = *(const short8*)&sBj[buf][boff + m2 * 512 + roff];
      }
#pragma unroll
      for (int m2 = 0; m2 < 4; ++m2)
#pragma unroll
        for (int n2 = 0; n2 < 4; ++n2)
          accB[m2][n2] = __builtin_amdgcn_mfma_f32_16x16x32_bf16(aB[m2], bB[n2], accB[m2][n2], 0, 0, 0);
    }
    __syncthreads();
    buf ^= 1;
  }
#undef STAGE

  // Epilogue. C/D layout (16x16x32): col = lane&15, row = (lane>>4)*4 + reg.
  const float fac = offd ? 2.0f : 1.0f;
  float pab = 0.f, paa = 0.f, pbb = 0.f;
  float rsa[4][4], rsb[4][4];
  float csa[4] = {0.f, 0.f, 0.f, 0.f}, csb[4] = {0.f, 0.f, 0.f, 0.f};
#pragma unroll
  for (int m2 = 0; m2 < 4; ++m2)
#pragma unroll
    for (int r = 0; r < 4; ++r) { rsa[m2][r] = 0.f; rsb[m2][r] = 0.f; }

  const int gi0 = ib * 128 + wr * 64;
  const int gj0 = jb * 128 + wc * 64;

#pragma unroll
  for (int m2 = 0; m2 < 4; ++m2) {
    const int gr = gi0 + m2 * 16 + kg * 4;
    const f32x4 nai = *(const f32x4*)&na[gr];
    const f32x4 nbi = *(const f32x4*)&nb[gr];
#pragma unroll
    for (int n2 = 0; n2 < 4; ++n2) {
      const int gc = gj0 + n2 * 16 + lrow;
      const float naj = na[gc];
      const float nbj = nb[gc];
      const f32x4 ga = accA[m2][n2];
      const f32x4 gb = accB[m2][n2];
#pragma unroll
      for (int r = 0; r < 4; ++r) {
        const float d2a = fmaxf(nai[r] + naj - 2.0f * ga[r], 1e-8f);
        const float d2b = fmaxf(nbi[r] + nbj - 2.0f * gb[r], 1e-8f);
        const float Da = sqrtf(d2a);
        const float Db = sqrtf(d2b);
        pab += Da * Db;
        paa += d2a;
        pbb += d2b;
        rsa[m2][r] += Da;
        rsb[m2][r] += Db;
        csa[n2] += Da;
        csb[n2] += Db;
      }
    }
  }

  // row sums: reduce across the 16 lanes sharing a row (lrow axis)
#pragma unroll
  for (int m2 = 0; m2 < 4; ++m2)
#pragma unroll
    for (int r = 0; r < 4; ++r) {
      float va = rsa[m2][r], vb = rsb[m2][r];
      va += __shfl_xor(va, 1); va += __shfl_xor(va, 2); va += __shfl_xor(va, 4); va += __shfl_xor(va, 8);
      vb += __shfl_xor(vb, 1); vb += __shfl_xor(vb, 2); vb += __shfl_xor(vb, 4); vb += __shfl_xor(vb, 8);
      if (lrow == 0) {
        const int gi = gi0 + m2 * 16 + kg * 4 + r;
        atomicAdd(&Ra[gi], va);
        atomicAdd(&Rb[gi], vb);
      }
    }

  // col sums (transpose contribution) only for off-diagonal tiles
  if (offd) {
#pragma unroll
    for (int n2 = 0; n2 < 4; ++n2) {
      float va = csa[n2], vb = csb[n2];
      va += __shfl_xor(va, 16); va += __shfl_xor(va, 32);
      vb += __shfl_xor(vb, 16); vb += __shfl_xor(vb, 32);
      if (kg == 0) {
        const int gj = gj0 + n2 * 16 + lrow;
        atomicAdd(&Ra[gj], va);
        atomicAdd(&Rb[gj], vb);
      }
    }
  }

  // scalar partials -> unique per-block slots (no contended atomics)
  float t1 = fac * pab, t2 = fac * paa, t3 = fac * pbb;
#pragma unroll
  for (int off = 32; off; off >>= 1) {
    t1 += __shfl_xor(t1, off); t2 += __shfl_xor(t2, off); t3 += __shfl_xor(t3, off);
  }
  if (lane == 0) { swred[w * 3 + 0] = t1; swred[w * 3 + 1] = t2; swred[w * 3 + 2] = t3; }
  __syncthreads();
  if (tid == 0) {
    double p0 = 0, p1 = 0, p2 = 0;
    for (int wv = 0; wv < 4; ++wv) { p0 += swred[wv * 3]; p1 += swred[wv * 3 + 1]; p2 += swred[wv * 3 + 2]; }
    scalPart[idx] = p0;
    scalPart[T + idx] = p1;
    scalPart[2 * T + idx] = p2;
  }
}

// ---------------------------------------------------------------------------
// Final combine (fp64 to survive the ~4-decade cancellation in S terms).
// ---------------------------------------------------------------------------
__global__ __launch_bounds__(256)
void finalize_kernel(const float* __restrict__ Ra, const float* __restrict__ Rb,
                     const double* __restrict__ scalPart, int T,
                     const float* __restrict__ coxo,
                     const float* __restrict__ iw, const float* __restrict__ ic,
                     float* __restrict__ out, int B)
{
  const int tid = threadIdx.x;
  double v[8];
#pragma unroll
  for (int k = 0; k < 8; ++k) v[k] = 0.0;
  for (int i = tid; i < B; i += 256) {
    const double a = Ra[i], b = Rb[i];
    v[0] += a; v[1] += b; v[2] += a * b; v[3] += a * a; v[4] += b * b;
  }
  for (int i = tid; i < T; i += 256) {
    v[5] += scalPart[i]; v[6] += scalPart[T + i]; v[7] += scalPart[2 * T + i];
  }
#pragma unroll
  for (int k = 0; k < 8; ++k)
#pragma unroll
    for (int off = 32; off; off >>= 1) v[k] += __shfl_xor(v[k], off);
  __shared__ double sred[32];
  const int w = tid >> 6;
  if ((tid & 63) == 0) {
#pragma unroll
    for (int k = 0; k < 8; ++k) sred[k * 4 + w] = v[k];
  }
  __syncthreads();
  if (tid == 0) {
    double r[8];
#pragma unroll
    for (int k = 0; k < 8; ++k) r[k] = sred[k * 4] + sred[k * 4 + 1] + sred[k * 4 + 2] + sred[k * 4 + 3];
    const double ta = r[0], tb = r[1], sab = r[2], saa = r[3], sbb = r[4];
    const double Pab = r[5], Paa = r[6], Pbb = r[7];
    const double n = (double)B;
    const double Sab = Pab - (2.0 / n) * sab + ta * tb / (n * n);
    const double Saa = Paa - (2.0 / n) * saa + ta * ta / (n * n);
    const double Sbb = Pbb - (2.0 / n) * sbb + tb * tb / (n * n);
    const double dcov = Sab / (n * n);
    const double va = Saa / (n * n);
    const double vb = Sbb / (n * n);
    const double l_cca = 1.0 - dcov / sqrt(fmax(va * vb, 1e-8));
    const double total = (double)coxo[0] + (double)coxo[1]
                       + (0.1 * l_cca + 0.05 * ((double)iw[0] + (double)ic[0]));
    out[0] = (float)total;
  }
}

// ---------------------------------------------------------------------------
extern "C" void kernel_launch(void* const* d_in, const int* in_sizes, int n_in,
                              void* d_out, int out_size, void* d_ws, size_t ws_size,
                              hipStream_t stream)
{
  (void)n_in; (void)out_size; (void)ws_size;
  const float* risk_os   = (const float*)d_in[0];
  const float* risk_rfs  = (const float*)d_in[1];
  const float* z_ct      = (const float*)d_in[2];
  const float* z_wsi     = (const float*)d_in[3];
  const float* intra_wsi = (const float*)d_in[4];
  const float* intra_ct  = (const float*)d_in[5];
  const int* evt_os  = (const int*)d_in[6];
  const int* tm_os   = (const int*)d_in[7];
  const int* evt_rfs = (const int*)d_in[8];
  const int* tm_rfs  = (const int*)d_in[9];

  const int B = in_sizes[0];        // 8192
  const int D = in_sizes[2] / B;    // 256
  const int nt = B / 128;           // 64
  const int T = nt * (nt + 1) / 2;  // 2080

  // ws layout (float units):
  // [0,B) Ra | [B,2B) Rb | [2B,2B+16) coxo/pad | [2B+16,3B+16) na |
  // [3B+16,4B+16) nb | [4B+16, +3T doubles) scalPart | then bf16 z copies
  float* ws = (float*)d_ws;
  float* Ra = ws;
  float* Rb = ws + B;
  float* coxo = ws + 2 * B;
  float* na  = ws + 2 * B + 16;
  float* nbv = ws + 3 * B + 16;
  double* scalPart = (double*)(ws + 4 * B + 16);
  unsigned short* zba = (unsigned short*)(ws + 4 * B + 16 + 6 * T);  // 3T doubles = 6T floats
  unsigned short* zbb = zba + (size_t)B * D;

  hipMemsetAsync(d_ws, 0, (size_t)(2 * B) * sizeof(float), stream);

  prep_kernel<<<(2 * B) / 4, 256, 0, stream>>>(z_ct, z_wsi, na, nbv, zba, zbb, B, D);
  cox_kernel<<<2, 1024, 0, stream>>>(risk_os, evt_os, tm_os, risk_rfs, evt_rfs, tm_rfs, coxo, B);
  dcor_kernel<<<T, 256, 0, stream>>>(zba, zbb, na, nbv, Ra, Rb, scalPart, T, nt, B, D);
  finalize_kernel<<<1, 256, 0, stream>>>(Ra, Rb, scalPart, T, coxo, intra_wsi, intra_ct, (float*)d_out, B);
}

// Round 4
// 189.150 us; speedup vs baseline: 3.7277x; 1.2857x over previous
//
#include <hip/hip_runtime.h>
#include <hip/hip_bf16.h>
#include <math.h>

typedef __attribute__((ext_vector_type(4))) float f32x4;
typedef __attribute__((ext_vector_type(8))) short short8;

#define NBINS 1000

__device__ __forceinline__ unsigned short f2bf(float x) {
  union { float f; unsigned u; } c; c.f = x;
  unsigned u = c.u;
  unsigned r = (u + 0x7FFFu + ((u >> 16) & 1u)) >> 16;  // RNE
  return (unsigned short)r;
}
__device__ __forceinline__ float bf2f(unsigned short h) {
  union { unsigned u; float f; } c; c.u = ((unsigned)h) << 16;
  return c.f;
}

// direct global -> LDS async copy, 16B per lane; LDS dest = base + lane*16
__device__ __forceinline__ void gl16(const void* g, void* l) {
  __builtin_amdgcn_global_load_lds(
      (const __attribute__((address_space(1))) unsigned int*)g,
      (__attribute__((address_space(3))) unsigned int*)l, 16, 0, 0);
}

// ---------------------------------------------------------------------------
// prep: round z to bf16 and write PANEL-PACKED + BANK-SWIZZLED:
//   packed[tile][kc][row 0..127][32 shorts], 16B-slot s -> s ^ ((row>>1)&3).
// This is the exact LDS image, so dcor stages with contiguous 1KB gl16 loads.
// Row norms computed from the ROUNDED values.
// ---------------------------------------------------------------------------
__global__ __launch_bounds__(256)
void prep_kernel(const float* __restrict__ za, const float* __restrict__ zb,
                 float* __restrict__ na, float* __restrict__ nb,
                 unsigned short* __restrict__ zpa, unsigned short* __restrict__ zpb,
                 int B, int D)
{
  const int row = blockIdx.x * 4 + (threadIdx.x >> 6);
  const int lane = threadIdx.x & 63;
  const float* src; float* dst; unsigned short* bd; int r;
  if (row < B) { src = za; dst = na; bd = zpa; r = row; }
  else         { src = zb; dst = nb; bd = zpb; r = row - B; }
  const int pt = r >> 7;
  const int rr = r & 127;
  const int sw = (rr >> 1) & 3;
  const size_t tbase = (size_t)pt * 128 * D;
  float s = 0.f;
  for (int c = lane * 4; c < D; c += 256) {
    const f32x4 v = *(const f32x4*)&src[(size_t)r * D + c];
    unsigned short h0 = f2bf(v[0]), h1 = f2bf(v[1]), h2 = f2bf(v[2]), h3 = f2bf(v[3]);
    union { unsigned short us[4]; uint2 u2; } pk;
    pk.us[0] = h0; pk.us[1] = h1; pk.us[2] = h2; pk.us[3] = h3;
    const int kc = c >> 5;
    const int wc = c & 31;
    const int sl = (wc >> 3) ^ sw;
    const int e = wc & 7;
    *(uint2*)&bd[tbase + kc * 4096 + rr * 32 + sl * 8 + e] = pk.u2;
    const float x0 = bf2f(h0), x1 = bf2f(h1), x2 = bf2f(h2), x3 = bf2f(h3);
    s += x0 * x0 + x1 * x1 + x2 * x2 + x3 * x3;
  }
#pragma unroll
  for (int off = 32; off; off >>= 1) s += __shfl_xor(s, off);
  if (lane == 0) dst[r] = s;
}

// ---------------------------------------------------------------------------
// Merged kernel: blocks 0,1 = Efron Cox losses (integer-time binning);
// blocks 2..T+1 = fused double-Gram dcor tiles (symmetric, jb >= ib).
// ---------------------------------------------------------------------------
__global__ __launch_bounds__(256)
void dcor_kernel(const unsigned short* __restrict__ zpa,
                 const unsigned short* __restrict__ zpb,
                 const float* __restrict__ na, const float* __restrict__ nb,
                 float* __restrict__ Ra, float* __restrict__ Rb,
                 double* __restrict__ scalPart,
                 const float* __restrict__ r0, const int* __restrict__ e0, const int* __restrict__ t0,
                 const float* __restrict__ r1, const int* __restrict__ e1, const int* __restrict__ t1,
                 float* __restrict__ coxo,
                 int T, int nt, int B, int D)
{
  __shared__ __align__(16) union SU {
    struct { short sAi[2][4096], sAj[2][4096], sBi[2][4096], sBj[2][4096]; double swred[12]; } g;
    struct { float sS[NBINS], sT[NBINS], sDc[NBINS], sc0[NBINS], sc1[NBINS], red[16], red3[48]; } c;
  } u;

  const int tid = threadIdx.x;
  const int bid = blockIdx.x;

  if (bid < 2) {
    // ---------------- Cox path (whole block uniform) ----------------
    const float* risk = bid ? r1 : r0;
    const int* evt = bid ? e1 : e0;
    const int* tm  = bid ? t1 : t0;
    const int NT = 256;

    float m = -3.0e38f;
    for (int i = tid; i < B; i += NT) m = fmaxf(m, risk[i]);
#pragma unroll
    for (int off = 32; off; off >>= 1) m = fmaxf(m, __shfl_xor(m, off));
    if ((tid & 63) == 0) u.c.red[tid >> 6] = m;
    __syncthreads();
    if (tid == 0) {
      float mm = u.c.red[0];
      for (int wv = 1; wv < 4; ++wv) mm = fmaxf(mm, u.c.red[wv]);
      u.c.red[0] = mm;
    }
    __syncthreads();
    const float maxr = u.c.red[0];

    for (int i = tid; i < NBINS; i += NT) { u.c.sS[i] = 0.f; u.c.sT[i] = 0.f; u.c.sDc[i] = 0.f; }
    __syncthreads();

    float sr = 0.f, nev = 0.f;
    for (int i = tid; i < B; i += NT) {
      const float r = risk[i];
      int t = tm[i];
      t = t < 0 ? 0 : (t >= NBINS ? NBINS - 1 : t);
      const float ex = expf(r - maxr);
      atomicAdd(&u.c.sS[t], ex);
      if (evt[i]) {
        atomicAdd(&u.c.sT[t], ex);
        atomicAdd(&u.c.sDc[t], 1.0f);
        sr += r; nev += 1.0f;
      }
    }
    __syncthreads();

    for (int i = tid; i < NBINS; i += NT) u.c.sc0[i] = u.c.sS[i];
    __syncthreads();
    float* pin = u.c.sc0; float* pout = u.c.sc1;
    for (int off = 1; off < NBINS; off <<= 1) {
      for (int i = tid; i < NBINS; i += NT) {
        float v = pin[i];
        if (i + off < NBINS) v += pin[i + off];
        pout[i] = v;
      }
      __syncthreads();
      float* tmp = pin; pin = pout; pout = tmp;
    }

    float ls = 0.f;
    for (int t = tid; t < NBINS; t += NT) {
      const float d = u.c.sDc[t];
      if (d > 0.f) {
        const float tes = u.c.sT[t];
        const float rs = pin[t];
        for (float l = 0.f; l < d - 0.5f; l += 1.f)
          ls += logf(rs - (l / d) * tes + 1e-12f);
      }
    }

    float v1 = sr, v2 = nev, v3 = ls;
#pragma unroll
    for (int off = 32; off; off >>= 1) {
      v1 += __shfl_xor(v1, off); v2 += __shfl_xor(v2, off); v3 += __shfl_xor(v3, off);
    }
    if ((tid & 63) == 0) { int wv = tid >> 6; u.c.red3[wv] = v1; u.c.red3[16 + wv] = v2; u.c.red3[32 + wv] = v3; }
    __syncthreads();
    if (tid == 0) {
      float SR = 0.f, NEV = 0.f, LS = 0.f;
      for (int wv = 0; wv < 4; ++wv) { SR += u.c.red3[wv]; NEV += u.c.red3[16 + wv]; LS += u.c.red3[32 + wv]; }
      coxo[bid] = -(SR - LS - NEV * maxr) / (NEV + 1e-12f);
    }
    return;
  }

  // ---------------- dcor path ----------------
  const int lane = tid & 63;
  const int w = tid >> 6;

  const int b2 = bid - 2;
  const int idx = ((T & 7) == 0) ? ((b2 & 7) * (T >> 3) + (b2 >> 3)) : b2;
  const double tn = (double)(2 * nt + 1);
  int ib = (int)((tn - sqrt(tn * tn - 8.0 * (double)idx)) * 0.5);
  if (ib < 0) ib = 0;
  if (ib > nt - 1) ib = nt - 1;
  while (((ib + 1) * nt - ((ib + 1) * ib) / 2) <= idx) ++ib;
  while ((ib * nt - (ib * (ib - 1)) / 2) > idx) --ib;
  const int jb = ib + (idx - (ib * nt - (ib * (ib - 1)) / 2));
  const bool offd = (jb != ib);

  // packed panel bases (each panel: 128*D shorts, k-chunk stride 4096 shorts)
  const unsigned short* pAi = zpa + (size_t)ib * 128 * D;
  const unsigned short* pAj = zpa + (size_t)jb * 128 * D;
  const unsigned short* pBi = zpb + (size_t)ib * 128 * D;
  const unsigned short* pBj = zpb + (size_t)jb * 128 * D;
  const int lso = w * 1024;             // wave's LDS segment (shorts)
  const int gso = w * 1024 + lane * 8;  // per-lane source offset (shorts)

#define STAGE(b, t)                                        \
  do { const size_t co = (size_t)(t) * 4096 + gso;         \
    gl16(pAi + co,       &u.g.sAi[b][lso]);                \
    gl16(pAi + co + 512, &u.g.sAi[b][lso + 512]);          \
    gl16(pAj + co,       &u.g.sAj[b][lso]);                \
    gl16(pAj + co + 512, &u.g.sAj[b][lso + 512]);          \
    gl16(pBi + co,       &u.g.sBi[b][lso]);                \
    gl16(pBi + co + 512, &u.g.sBi[b][lso + 512]);          \
    gl16(pBj + co,       &u.g.sBj[b][lso]);                \
    gl16(pBj + co + 512, &u.g.sBj[b][lso + 512]);          \
  } while (0)

  // fragment geometry
  const int wr = w >> 1, wc = w & 1;
  const int lrow = lane & 15;
  const int kg = lane >> 4;
  const int hr = (lrow >> 1) & 3;
  const int roff = lrow * 32 + ((kg ^ hr) << 3);
  const int aoff = wr * 2048;
  const int boff = wc * 2048;

  const f32x4 Z4 = {0.f, 0.f, 0.f, 0.f};
  f32x4 accA[4][4], accB[4][4];
#pragma unroll
  for (int m = 0; m < 4; ++m)
#pragma unroll
    for (int n = 0; n < 4; ++n) { accA[m][n] = Z4; accB[m][n] = Z4; }

  int buf = 0;
  STAGE(0, 0);
  __syncthreads();

  const int nk = D >> 5;  // 8
  for (int t = 0; t < nk; ++t) {
    if (t + 1 < nk) { const int nb2 = buf ^ 1; STAGE(nb2, t + 1); }
    {
      short8 aA[4], bA[4];
#pragma unroll
      for (int m2 = 0; m2 < 4; ++m2) {
        aA[m2] = *(const short8*)&u.g.sAi[buf][aoff + m2 * 512 + roff];
        bA[m2] = *(const short8*)&u.g.sAj[buf][boff + m2 * 512 + roff];
      }
#pragma unroll
      for (int m2 = 0; m2 < 4; ++m2)
#pragma unroll
        for (int n2 = 0; n2 < 4; ++n2)
          accA[m2][n2] = __builtin_amdgcn_mfma_f32_16x16x32_bf16(aA[m2], bA[n2], accA[m2][n2], 0, 0, 0);
    }
    {
      short8 aB[4], bB[4];
#pragma unroll
      for (int m2 = 0; m2 < 4; ++m2) {
        aB[m2] = *(const short8*)&u.g.sBi[buf][aoff + m2 * 512 + roff];
        bB[m2] = *(const short8*)&u.g.sBj[buf][boff + m2 * 512 + roff];
      }
#pragma unroll
      for (int m2 = 0; m2 < 4; ++m2)
#pragma unroll
        for (int n2 = 0; n2 < 4; ++n2)
          accB[m2][n2] = __builtin_amdgcn_mfma_f32_16x16x32_bf16(aB[m2], bB[n2], accB[m2][n2], 0, 0, 0);
    }
    __syncthreads();
    buf ^= 1;
  }
#undef STAGE

  // Epilogue. C/D layout (16x16x32): col = lane&15, row = (lane>>4)*4 + reg.
  const float fac = offd ? 2.0f : 1.0f;
  float pab = 0.f, paa = 0.f, pbb = 0.f;
  float rsa[4][4], rsb[4][4];
  float csa[4] = {0.f, 0.f, 0.f, 0.f}, csb[4] = {0.f, 0.f, 0.f, 0.f};
#pragma unroll
  for (int m2 = 0; m2 < 4; ++m2)
#pragma unroll
    for (int r = 0; r < 4; ++r) { rsa[m2][r] = 0.f; rsb[m2][r] = 0.f; }

  const int gi0 = ib * 128 + wr * 64;
  const int gj0 = jb * 128 + wc * 64;

#pragma unroll
  for (int m2 = 0; m2 < 4; ++m2) {
    const int gr = gi0 + m2 * 16 + kg * 4;
    const f32x4 nai = *(const f32x4*)&na[gr];
    const f32x4 nbi = *(const f32x4*)&nb[gr];
#pragma unroll
    for (int n2 = 0; n2 < 4; ++n2) {
      const int gc = gj0 + n2 * 16 + lrow;
      const float naj = na[gc];
      const float nbj = nb[gc];
      const f32x4 ga = accA[m2][n2];
      const f32x4 gb = accB[m2][n2];
#pragma unroll
      for (int r = 0; r < 4; ++r) {
        const float d2a = fmaxf(nai[r] + naj - 2.0f * ga[r], 1e-8f);
        const float d2b = fmaxf(nbi[r] + nbj - 2.0f * gb[r], 1e-8f);
        const float Da = sqrtf(d2a);
        const float Db = sqrtf(d2b);
        pab += Da * Db;
        paa += d2a;
        pbb += d2b;
        rsa[m2][r] += Da;
        rsb[m2][r] += Db;
        csa[n2] += Da;
        csb[n2] += Db;
      }
    }
  }

#pragma unroll
  for (int m2 = 0; m2 < 4; ++m2)
#pragma unroll
    for (int r = 0; r < 4; ++r) {
      float va = rsa[m2][r], vb = rsb[m2][r];
      va += __shfl_xor(va, 1); va += __shfl_xor(va, 2); va += __shfl_xor(va, 4); va += __shfl_xor(va, 8);
      vb += __shfl_xor(vb, 1); vb += __shfl_xor(vb, 2); vb += __shfl_xor(vb, 4); vb += __shfl_xor(vb, 8);
      if (lrow == 0) {
        const int gi = gi0 + m2 * 16 + kg * 4 + r;
        atomicAdd(&Ra[gi], va);
        atomicAdd(&Rb[gi], vb);
      }
    }

  if (offd) {
#pragma unroll
    for (int n2 = 0; n2 < 4; ++n2) {
      float va = csa[n2], vb = csb[n2];
      va += __shfl_xor(va, 16); va += __shfl_xor(va, 32);
      vb += __shfl_xor(vb, 16); vb += __shfl_xor(vb, 32);
      if (kg == 0) {
        const int gj = gj0 + n2 * 16 + lrow;
        atomicAdd(&Ra[gj], va);
        atomicAdd(&Rb[gj], vb);
      }
    }
  }

  float q1 = fac * pab, q2 = fac * paa, q3 = fac * pbb;
#pragma unroll
  for (int off = 32; off; off >>= 1) {
    q1 += __shfl_xor(q1, off); q2 += __shfl_xor(q2, off); q3 += __shfl_xor(q3, off);
  }
  if (lane == 0) { u.g.swred[w * 3 + 0] = q1; u.g.swred[w * 3 + 1] = q2; u.g.swred[w * 3 + 2] = q3; }
  __syncthreads();
  if (tid == 0) {
    double p0 = 0, p1 = 0, p2 = 0;
    for (int wv = 0; wv < 4; ++wv) { p0 += u.g.swred[wv * 3]; p1 += u.g.swred[wv * 3 + 1]; p2 += u.g.swred[wv * 3 + 2]; }
    scalPart[idx] = p0;
    scalPart[T + idx] = p1;
    scalPart[2 * T + idx] = p2;
  }
}

// ---------------------------------------------------------------------------
// Final combine (fp64 to survive the ~4-decade cancellation in S terms).
// ---------------------------------------------------------------------------
__global__ __launch_bounds__(256)
void finalize_kernel(const float* __restrict__ Ra, const float* __restrict__ Rb,
                     const double* __restrict__ scalPart, int T,
                     const float* __restrict__ coxo,
                     const float* __restrict__ iw, const float* __restrict__ ic,
                     float* __restrict__ out, int B)
{
  const int tid = threadIdx.x;
  double v[8];
#pragma unroll
  for (int k = 0; k < 8; ++k) v[k] = 0.0;
  for (int i = tid; i < B; i += 256) {
    const double a = Ra[i], b = Rb[i];
    v[0] += a; v[1] += b; v[2] += a * b; v[3] += a * a; v[4] += b * b;
  }
  for (int i = tid; i < T; i += 256) {
    v[5] += scalPart[i]; v[6] += scalPart[T + i]; v[7] += scalPart[2 * T + i];
  }
#pragma unroll
  for (int k = 0; k < 8; ++k)
#pragma unroll
    for (int off = 32; off; off >>= 1) v[k] += __shfl_xor(v[k], off);
  __shared__ double sred[32];
  const int w = tid >> 6;
  if ((tid & 63) == 0) {
#pragma unroll
    for (int k = 0; k < 8; ++k) sred[k * 4 + w] = v[k];
  }
  __syncthreads();
  if (tid == 0) {
    double r[8];
#pragma unroll
    for (int k = 0; k < 8; ++k) r[k] = sred[k * 4] + sred[k * 4 + 1] + sred[k * 4 + 2] + sred[k * 4 + 3];
    const double ta = r[0], tb = r[1], sab = r[2], saa = r[3], sbb = r[4];
    const double Pab = r[5], Paa = r[6], Pbb = r[7];
    const double n = (double)B;
    const double Sab = Pab - (2.0 / n) * sab + ta * tb / (n * n);
    const double Saa = Paa - (2.0 / n) * saa + ta * ta / (n * n);
    const double Sbb = Pbb - (2.0 / n) * sbb + tb * tb / (n * n);
    const double dcov = Sab / (n * n);
    const double va = Saa / (n * n);
    const double vb = Sbb / (n * n);
    const double l_cca = 1.0 - dcov / sqrt(fmax(va * vb, 1e-8));
    const double total = (double)coxo[0] + (double)coxo[1]
                       + (0.1 * l_cca + 0.05 * ((double)iw[0] + (double)ic[0]));
    out[0] = (float)total;
  }
}

// ---------------------------------------------------------------------------
extern "C" void kernel_launch(void* const* d_in, const int* in_sizes, int n_in,
                              void* d_out, int out_size, void* d_ws, size_t ws_size,
                              hipStream_t stream)
{
  (void)n_in; (void)out_size; (void)ws_size;
  const float* risk_os   = (const float*)d_in[0];
  const float* risk_rfs  = (const float*)d_in[1];
  const float* z_ct      = (const float*)d_in[2];
  const float* z_wsi     = (const float*)d_in[3];
  const float* intra_wsi = (const float*)d_in[4];
  const float* intra_ct  = (const float*)d_in[5];
  const int* evt_os  = (const int*)d_in[6];
  const int* tm_os   = (const int*)d_in[7];
  const int* evt_rfs = (const int*)d_in[8];
  const int* tm_rfs  = (const int*)d_in[9];

  const int B = in_sizes[0];        // 8192
  const int D = in_sizes[2] / B;    // 256
  const int nt = B / 128;           // 64
  const int T = nt * (nt + 1) / 2;  // 2080

  // ws layout (float units):
  // [0,B) Ra | [B,2B) Rb | [2B,2B+16) coxo/pad | [2B+16,3B+16) na |
  // [3B+16,4B+16) nb | scalPart (3T doubles) | packed bf16 z copies
  float* ws = (float*)d_ws;
  float* Ra = ws;
  float* Rb = ws + B;
  float* coxo = ws + 2 * B;
  float* na  = ws + 2 * B + 16;
  float* nbv = ws + 3 * B + 16;
  double* scalPart = (double*)(ws + 4 * B + 16);
  unsigned short* zpa = (unsigned short*)(ws + 4 * B + 16 + 6 * T);
  unsigned short* zpb = zpa + (size_t)B * D;

  (void)hipMemsetAsync(d_ws, 0, (size_t)(2 * B) * sizeof(float), stream);

  prep_kernel<<<(2 * B) / 4, 256, 0, stream>>>(z_ct, z_wsi, na, nbv, zpa, zpb, B, D);
  dcor_kernel<<<T + 2, 256, 0, stream>>>(zpa, zpb, na, nbv, Ra, Rb, scalPart,
                                         risk_os, evt_os, tm_os, risk_rfs, evt_rfs, tm_rfs,
                                         coxo, T, nt, B, D);
  finalize_kernel<<<1, 256, 0, stream>>>(Ra, Rb, scalPart, T, coxo, intra_wsi, intra_ct, (float*)d_out, B);
}

// Round 6
// 127.209 us; speedup vs baseline: 5.5427x; 1.4869x over previous
//
#include <hip/hip_runtime.h>
#include <hip/hip_bf16.h>
#include <math.h>

typedef __attribute__((ext_vector_type(4))) float f32x4;
typedef __attribute__((ext_vector_type(8))) short short8;

#define NBINS 1000

__device__ __forceinline__ unsigned short f2bf(float x) {
  union { float f; unsigned u; } c; c.f = x;
  unsigned u = c.u;
  unsigned r = (u + 0x7FFFu + ((u >> 16) & 1u)) >> 16;  // RNE
  return (unsigned short)r;
}
__device__ __forceinline__ float bf2f(unsigned short h) {
  union { unsigned u; float f; } c; c.u = ((unsigned)h) << 16;
  return c.f;
}

// direct global -> LDS async copy, 16B per lane; LDS dest = base + lane*16
__device__ __forceinline__ void gl16(const void* g, void* l) {
  __builtin_amdgcn_global_load_lds(
      (const __attribute__((address_space(1))) unsigned int*)g,
      (__attribute__((address_space(3))) unsigned int*)l, 16, 0, 0);
}

// ---------------------------------------------------------------------------
// prep: round z to bf16 and write PANEL-PACKED + BANK-SWIZZLED:
//   packed[tile][kc][row 0..127][32 shorts], 16B-slot s -> s ^ ((row>>1)&3).
// Exact LDS image: dcor stages with contiguous 1KB gl16 segments.
// ---------------------------------------------------------------------------
__global__ __launch_bounds__(256)
void prep_kernel(const float* __restrict__ za, const float* __restrict__ zb,
                 float* __restrict__ na, float* __restrict__ nb,
                 unsigned short* __restrict__ zpa, unsigned short* __restrict__ zpb,
                 int B, int D)
{
  const int row = blockIdx.x * 4 + (threadIdx.x >> 6);
  const int lane = threadIdx.x & 63;
  const float* src; float* dst; unsigned short* bd; int r;
  if (row < B) { src = za; dst = na; bd = zpa; r = row; }
  else         { src = zb; dst = nb; bd = zpb; r = row - B; }
  const int pt = r >> 7;
  const int rr = r & 127;
  const int sw = (rr >> 1) & 3;
  const size_t tbase = (size_t)pt * 128 * D;
  float s = 0.f;
  for (int c = lane * 4; c < D; c += 256) {
    const f32x4 v = *(const f32x4*)&src[(size_t)r * D + c];
    unsigned short h0 = f2bf(v[0]), h1 = f2bf(v[1]), h2 = f2bf(v[2]), h3 = f2bf(v[3]);
    union { unsigned short us[4]; uint2 u2; } pk;
    pk.us[0] = h0; pk.us[1] = h1; pk.us[2] = h2; pk.us[3] = h3;
    const int kc = c >> 5;
    const int wc = c & 31;
    const int sl = (wc >> 3) ^ sw;
    const int e = wc & 7;
    *(uint2*)&bd[tbase + kc * 4096 + rr * 32 + sl * 8 + e] = pk.u2;
    const float x0 = bf2f(h0), x1 = bf2f(h1), x2 = bf2f(h2), x3 = bf2f(h3);
    s += x0 * x0 + x1 * x1 + x2 * x2 + x3 * x3;
  }
#pragma unroll
  for (int off = 32; off; off >>= 1) s += __shfl_xor(s, off);
  if (lane == 0) dst[r] = s;
}

// ---------------------------------------------------------------------------
// Merged kernel, grid = 512 (perfect 2/CU packing):
//   blocks 0,1   : Efron Cox losses (integer-time binning)
//   blocks 2..511: persistent dcor blocks, 4-5 consecutive triangular tiles,
//                  flat (tile,k) pipeline with counted vmcnt + raw barriers.
// ---------------------------------------------------------------------------
__global__ __launch_bounds__(256, 2)
void dcor_kernel(const unsigned short* __restrict__ zpa,
                 const unsigned short* __restrict__ zpb,
                 const float* __restrict__ na, const float* __restrict__ nb,
                 float* __restrict__ Ra, float* __restrict__ Rb,
                 double* __restrict__ scalPart,
                 const float* __restrict__ r0, const int* __restrict__ e0, const int* __restrict__ t0,
                 const float* __restrict__ r1, const int* __restrict__ e1, const int* __restrict__ t1,
                 float* __restrict__ coxo,
                 int T, int nt, int B, int D)
{
  __shared__ __align__(16) union SU {
    short g[8][4096];  // [panel*2 + buf][k-chunk image]; Ai=0 Aj=2 Bi=4 Bj=6
    struct { float sS[NBINS], sT[NBINS], sDc[NBINS], sc0[NBINS], sc1[NBINS], red[16], red3[48]; } c;
  } u;

  const int tid = threadIdx.x;
  const int bid = blockIdx.x;

  if (bid < 2) {
    // ---------------- Cox path ----------------
    const float* risk = bid ? r1 : r0;
    const int* evt = bid ? e1 : e0;
    const int* tm  = bid ? t1 : t0;
    const int NT = 256;

    float m = -3.0e38f;
    for (int i = tid; i < B; i += NT) m = fmaxf(m, risk[i]);
#pragma unroll
    for (int off = 32; off; off >>= 1) m = fmaxf(m, __shfl_xor(m, off));
    if ((tid & 63) == 0) u.c.red[tid >> 6] = m;
    __syncthreads();
    if (tid == 0) {
      float mm = u.c.red[0];
      for (int wv = 1; wv < 4; ++wv) mm = fmaxf(mm, u.c.red[wv]);
      u.c.red[0] = mm;
    }
    __syncthreads();
    const float maxr = u.c.red[0];

    for (int i = tid; i < NBINS; i += NT) { u.c.sS[i] = 0.f; u.c.sT[i] = 0.f; u.c.sDc[i] = 0.f; }
    __syncthreads();

    float sr = 0.f, nev = 0.f;
    for (int i = tid; i < B; i += NT) {
      const float r = risk[i];
      int t = tm[i];
      t = t < 0 ? 0 : (t >= NBINS ? NBINS - 1 : t);
      const float ex = expf(r - maxr);
      atomicAdd(&u.c.sS[t], ex);
      if (evt[i]) {
        atomicAdd(&u.c.sT[t], ex);
        atomicAdd(&u.c.sDc[t], 1.0f);
        sr += r; nev += 1.0f;
      }
    }
    __syncthreads();

    for (int i = tid; i < NBINS; i += NT) u.c.sc0[i] = u.c.sS[i];
    __syncthreads();
    float* pin = u.c.sc0; float* pout = u.c.sc1;
    for (int off = 1; off < NBINS; off <<= 1) {
      for (int i = tid; i < NBINS; i += NT) {
        float v = pin[i];
        if (i + off < NBINS) v += pin[i + off];
        pout[i] = v;
      }
      __syncthreads();
      float* tmp = pin; pin = pout; pout = tmp;
    }

    float ls = 0.f;
    for (int t = tid; t < NBINS; t += NT) {
      const float d = u.c.sDc[t];
      if (d > 0.f) {
        const float tes = u.c.sT[t];
        const float rs = pin[t];
        for (float l = 0.f; l < d - 0.5f; l += 1.f)
          ls += logf(rs - (l / d) * tes + 1e-12f);
      }
    }

    float v1 = sr, v2 = nev, v3 = ls;
#pragma unroll
    for (int off = 32; off; off >>= 1) {
      v1 += __shfl_xor(v1, off); v2 += __shfl_xor(v2, off); v3 += __shfl_xor(v3, off);
    }
    if ((tid & 63) == 0) { int wv = tid >> 6; u.c.red3[wv] = v1; u.c.red3[16 + wv] = v2; u.c.red3[32 + wv] = v3; }
    __syncthreads();
    if (tid == 0) {
      float SR = 0.f, NEV = 0.f, LS = 0.f;
      for (int wv = 0; wv < 4; ++wv) { SR += u.c.red3[wv]; NEV += u.c.red3[16 + wv]; LS += u.c.red3[32 + wv]; }
      coxo[bid] = -(SR - LS - NEV * maxr) / (NEV + 1e-12f);
    }
    return;
  }

  // ---------------- dcor path ----------------
  const int lane = tid & 63;
  const int w = tid >> 6;
  const int p = bid - 2;  // 0..509

  // XCD-bijective banded block->q map (510 = 6*64 + 2*63)
  const int xcd = p & 7, pos = p >> 3;
  const int q = (xcd < 6 ? xcd * 64 : 384 + (xcd - 6) * 63) + pos;
  // q -> contiguous tile range; 40 blocks (q%13==0) take 5 tiles, rest 4
  const int start = 4 * q + (q + 12) / 13;
  const int cnt = 4 + ((q % 13) == 0 ? 1 : 0);

  // decode start -> (ib0, jb0) in triangular order (jb >= ib)
  const double tn = (double)(2 * nt + 1);
  int ib0 = (int)((tn - sqrt(tn * tn - 8.0 * (double)start)) * 0.5);
  if (ib0 < 0) ib0 = 0;
  if (ib0 > nt - 1) ib0 = nt - 1;
  while (((ib0 + 1) * nt - ((ib0 + 1) * ib0) / 2) <= start) ++ib0;
  while ((ib0 * nt - (ib0 * (ib0 - 1)) / 2) > start) --ib0;
  const int jb0 = ib0 + (start - (ib0 * nt - (ib0 * (ib0 - 1)) / 2));

  // staging geometry
  const int lso = w * 1024;             // wave's LDS segment (shorts)
  const int gso = w * 1024 + lane * 8;  // per-lane source offset (shorts)

  // staging tile state (tile of step being staged) + compute tile state
  int sib = ib0, sjb = jb0;
  int cib = ib0, cjb = jb0;
  const unsigned short* gAi = zpa + (size_t)sib * 128 * D;
  const unsigned short* gAj = zpa + (size_t)sjb * 128 * D;
  const unsigned short* gBi = zpb + (size_t)sib * 128 * D;
  const unsigned short* gBj = zpb + (size_t)sjb * 128 * D;

#define STAGE(par_, kk_) do {                              \
    const size_t co_ = (size_t)(kk_) * 4096 + gso;         \
    gl16(gAi + co_,       &u.g[0 + (par_)][lso]);          \
    gl16(gAi + co_ + 512, &u.g[0 + (par_)][lso + 512]);    \
    gl16(gAj + co_,       &u.g[2 + (par_)][lso]);          \
    gl16(gAj + co_ + 512, &u.g[2 + (par_)][lso + 512]);    \
    gl16(gBi + co_,       &u.g[4 + (par_)][lso]);          \
    gl16(gBi + co_ + 512, &u.g[4 + (par_)][lso + 512]);    \
    gl16(gBj + co_,       &u.g[6 + (par_)][lso]);          \
    gl16(gBj + co_ + 512, &u.g[6 + (par_)][lso + 512]);    \
  } while (0)

  // fragment geometry
  const int wr = w >> 1, wc = w & 1;
  const int lrow = lane & 15;
  const int kg = lane >> 4;
  const int hr = (lrow >> 1) & 3;
  const int roff = lrow * 32 + ((kg ^ hr) << 3);
  const int aoff = wr * 2048;
  const int boff = wc * 2048;

  const f32x4 Z4 = {0.f, 0.f, 0.f, 0.f};
  f32x4 accA[4][4], accB[4][4];
#pragma unroll
  for (int m = 0; m < 4; ++m)
#pragma unroll
    for (int n = 0; n < 4; ++n) { accA[m][n] = Z4; accB[m][n] = Z4; }

  const int S = cnt * 8;
  // prologue: stage steps 0,1 (tile0 k=0,1) into buffers 0,1
  STAGE(0, 0);
  STAGE(1, 1);

  for (int s = 0; s < S; ++s) {
    const int k = s & 7;
    const int par = s & 1;

    // stage(s) landed; stage(s+1)'s 8 may remain in flight
    if (s < S - 1) asm volatile("s_waitcnt vmcnt(8)" ::: "memory");
    else           asm volatile("s_waitcnt vmcnt(0)" ::: "memory");
    __builtin_amdgcn_sched_barrier(0);
    __builtin_amdgcn_s_barrier();
    __builtin_amdgcn_sched_barrier(0);

    {
      const short* lAi = u.g[0 + par];
      const short* lAj = u.g[2 + par];
      const short* lBi = u.g[4 + par];
      const short* lBj = u.g[6 + par];
      short8 aA[4], bA[4];
#pragma unroll
      for (int m2 = 0; m2 < 4; ++m2) {
        aA[m2] = *(const short8*)&lAi[aoff + m2 * 512 + roff];
        bA[m2] = *(const short8*)&lAj[boff + m2 * 512 + roff];
      }
#pragma unroll
      for (int m2 = 0; m2 < 4; ++m2)
#pragma unroll
        for (int n2 = 0; n2 < 4; ++n2)
          accA[m2][n2] = __builtin_amdgcn_mfma_f32_16x16x32_bf16(aA[m2], bA[n2], accA[m2][n2], 0, 0, 0);
      short8 aB[4], bB[4];
#pragma unroll
      for (int m2 = 0; m2 < 4; ++m2) {
        aB[m2] = *(const short8*)&lBi[aoff + m2 * 512 + roff];
        bB[m2] = *(const short8*)&lBj[boff + m2 * 512 + roff];
      }
#pragma unroll
      for (int m2 = 0; m2 < 4; ++m2)
#pragma unroll
        for (int n2 = 0; n2 < 4; ++n2)
          accB[m2][n2] = __builtin_amdgcn_mfma_f32_16x16x32_bf16(aB[m2], bB[n2], accB[m2][n2], 0, 0, 0);
    }

    __builtin_amdgcn_sched_barrier(0);
    __builtin_amdgcn_s_barrier();
    __builtin_amdgcn_sched_barrier(0);

    // issue stage for step s+2 into the buffer we just finished reading
    if (s + 2 < S) {
      const int s2 = s + 2;
      if ((s2 & 7) == 0) {  // s+2 starts a new tile
        if (++sjb == nt) { ++sib; sjb = sib; }
        gAi = zpa + (size_t)sib * 128 * D;
        gAj = zpa + (size_t)sjb * 128 * D;
        gBi = zpb + (size_t)sib * 128 * D;
        gBj = zpb + (size_t)sjb * 128 * D;
      }
      STAGE(par, s2 & 7);
    }

    if (k == 7) {
      // ---------------- epilogue for tile (cib,cjb) ----------------
      const bool offd = (cjb != cib);
      const float fac = offd ? 2.0f : 1.0f;
      float pab = 0.f, paa = 0.f, pbb = 0.f;
      float rsa[4][4], rsb[4][4];
      float csa[4] = {0.f, 0.f, 0.f, 0.f}, csb[4] = {0.f, 0.f, 0.f, 0.f};
#pragma unroll
      for (int m2 = 0; m2 < 4; ++m2)
#pragma unroll
        for (int r = 0; r < 4; ++r) { rsa[m2][r] = 0.f; rsb[m2][r] = 0.f; }

      const int gi0 = cib * 128 + wr * 64;
      const int gj0 = cjb * 128 + wc * 64;

#pragma unroll
      for (int m2 = 0; m2 < 4; ++m2) {
        const int gr = gi0 + m2 * 16 + kg * 4;
        const f32x4 nai = *(const f32x4*)&na[gr];
        const f32x4 nbi = *(const f32x4*)&nb[gr];
#pragma unroll
        for (int n2 = 0; n2 < 4; ++n2) {
          const int gc = gj0 + n2 * 16 + lrow;
          const float naj = na[gc];
          const float nbj = nb[gc];
          const f32x4 ga = accA[m2][n2];
          const f32x4 gb = accB[m2][n2];
#pragma unroll
          for (int r = 0; r < 4; ++r) {
            const float d2a = fmaxf(nai[r] + naj - 2.0f * ga[r], 1e-8f);
            const float d2b = fmaxf(nbi[r] + nbj - 2.0f * gb[r], 1e-8f);
            const float Da = __builtin_amdgcn_sqrtf(d2a);
            const float Db = __builtin_amdgcn_sqrtf(d2b);
            pab += Da * Db;
            paa += d2a;
            pbb += d2b;
            rsa[m2][r] += Da;
            rsb[m2][r] += Db;
            csa[n2] += Da;
            csb[n2] += Db;
          }
        }
      }

#pragma unroll
      for (int m2 = 0; m2 < 4; ++m2)
#pragma unroll
        for (int r = 0; r < 4; ++r) {
          float va = rsa[m2][r], vb = rsb[m2][r];
          va += __shfl_xor(va, 1); va += __shfl_xor(va, 2); va += __shfl_xor(va, 4); va += __shfl_xor(va, 8);
          vb += __shfl_xor(vb, 1); vb += __shfl_xor(vb, 2); vb += __shfl_xor(vb, 4); vb += __shfl_xor(vb, 8);
          if (lrow == 0) {
            const int gi = gi0 + m2 * 16 + kg * 4 + r;
            atomicAdd(&Ra[gi], va);
            atomicAdd(&Rb[gi], vb);
          }
        }

      if (offd) {
#pragma unroll
        for (int n2 = 0; n2 < 4; ++n2) {
          float va = csa[n2], vb = csb[n2];
          va += __shfl_xor(va, 16); va += __shfl_xor(va, 32);
          vb += __shfl_xor(vb, 16); vb += __shfl_xor(vb, 32);
          if (kg == 0) {
            const int gj = gj0 + n2 * 16 + lrow;
            atomicAdd(&Ra[gj], va);
            atomicAdd(&Rb[gj], vb);
          }
        }
      }

      float q1 = fac * pab, q2 = fac * paa, q3 = fac * pbb;
#pragma unroll
      for (int off = 32; off; off >>= 1) {
        q1 += __shfl_xor(q1, off); q2 += __shfl_xor(q2, off); q3 += __shfl_xor(q3, off);
      }
      if (lane == 0) {  // unique per-(tile,wave) slot: no atomics, no LDS, no sync
        const int ctile = start + (s >> 3);
        double* sp = scalPart + (size_t)ctile * 12 + w * 3;
        sp[0] = (double)q1; sp[1] = (double)q2; sp[2] = (double)q3;
      }

      // advance compute tile, reset accumulators
      if (++cjb == nt) { ++cib; cjb = cib; }
#pragma unroll
      for (int m2 = 0; m2 < 4; ++m2)
#pragma unroll
        for (int n2 = 0; n2 < 4; ++n2) { accA[m2][n2] = Z4; accB[m2][n2] = Z4; }
    }
  }
#undef STAGE
}

// ---------------------------------------------------------------------------
// Final combine (fp64 to survive the ~4-decade cancellation in S terms).
// ---------------------------------------------------------------------------
__global__ __launch_bounds__(256)
void finalize_kernel(const float* __restrict__ Ra, const float* __restrict__ Rb,
                     const double* __restrict__ scalPart, int T,
                     const float* __restrict__ coxo,
                     const float* __restrict__ iw, const float* __restrict__ ic,
                     float* __restrict__ out, int B)
{
  const int tid = threadIdx.x;
  double v[8];
#pragma unroll
  for (int k = 0; k < 8; ++k) v[k] = 0.0;
  for (int i = tid; i < B; i += 256) {
    const double a = Ra[i], b = Rb[i];
    v[0] += a; v[1] += b; v[2] += a * b; v[3] += a * a; v[4] += b * b;
  }
  for (int i = tid; i < T; i += 256) {
    const double* sp = scalPart + (size_t)i * 12;
    v[5] += sp[0] + sp[3] + sp[6] + sp[9];
    v[6] += sp[1] + sp[4] + sp[7] + sp[10];
    v[7] += sp[2] + sp[5] + sp[8] + sp[11];
  }
#pragma unroll
  for (int k = 0; k < 8; ++k)
#pragma unroll
    for (int off = 32; off; off >>= 1) v[k] += __shfl_xor(v[k], off);
  __shared__ double sred[32];
  const int w = tid >> 6;
  if ((tid & 63) == 0) {
#pragma unroll
    for (int k = 0; k < 8; ++k) sred[k * 4 + w] = v[k];
  }
  __syncthreads();
  if (tid == 0) {
    double r[8];
#pragma unroll
    for (int k = 0; k < 8; ++k) r[k] = sred[k * 4] + sred[k * 4 + 1] + sred[k * 4 + 2] + sred[k * 4 + 3];
    const double ta = r[0], tb = r[1], sab = r[2], saa = r[3], sbb = r[4];
    const double Pab = r[5], Paa = r[6], Pbb = r[7];
    const double n = (double)B;
    const double Sab = Pab - (2.0 / n) * sab + ta * tb / (n * n);
    const double Saa = Paa - (2.0 / n) * saa + ta * ta / (n * n);
    const double Sbb = Pbb - (2.0 / n) * sbb + tb * tb / (n * n);
    const double dcov = Sab / (n * n);
    const double va = Saa / (n * n);
    const double vb = Sbb / (n * n);
    const double l_cca = 1.0 - dcov / sqrt(fmax(va * vb, 1e-8));
    const double total = (double)coxo[0] + (double)coxo[1]
                       + (0.1 * l_cca + 0.05 * ((double)iw[0] + (double)ic[0]));
    out[0] = (float)total;
  }
}

// ---------------------------------------------------------------------------
extern "C" void kernel_launch(void* const* d_in, const int* in_sizes, int n_in,
                              void* d_out, int out_size, void* d_ws, size_t ws_size,
                              hipStream_t stream)
{
  (void)n_in; (void)out_size; (void)ws_size;
  const float* risk_os   = (const float*)d_in[0];
  const float* risk_rfs  = (const float*)d_in[1];
  const float* z_ct      = (const float*)d_in[2];
  const float* z_wsi     = (const float*)d_in[3];
  const float* intra_wsi = (const float*)d_in[4];
  const float* intra_ct  = (const float*)d_in[5];
  const int* evt_os  = (const int*)d_in[6];
  const int* tm_os   = (const int*)d_in[7];
  const int* evt_rfs = (const int*)d_in[8];
  const int* tm_rfs  = (const int*)d_in[9];

  const int B = in_sizes[0];        // 8192
  const int D = in_sizes[2] / B;    // 256
  const int nt = B / 128;           // 64
  const int T = nt * (nt + 1) / 2;  // 2080

  // ws layout (float units):
  // [0,B) Ra | [B,2B) Rb | [2B,2B+16) coxo/pad | [2B+16,3B+16) na |
  // [3B+16,4B+16) nb | scalPart (12T doubles = 24T floats) | packed bf16 z
  float* ws = (float*)d_ws;
  float* Ra = ws;
  float* Rb = ws + B;
  float* coxo = ws + 2 * B;
  float* na  = ws + 2 * B + 16;
  float* nbv = ws + 3 * B + 16;
  double* scalPart = (double*)(ws + 4 * B + 16);
  unsigned short* zpa = (unsigned short*)(ws + 4 * B + 16 + 24 * T);
  unsigned short* zpb = zpa + (size_t)B * D;

  (void)hipMemsetAsync(d_ws, 0, (size_t)(2 * B) * sizeof(float), stream);

  prep_kernel<<<(2 * B) / 4, 256, 0, stream>>>(z_ct, z_wsi, na, nbv, zpa, zpb, B, D);
  dcor_kernel<<<512, 256, 0, stream>>>(zpa, zpb, na, nbv, Ra, Rb, scalPart,
                                       risk_os, evt_os, tm_os, risk_rfs, evt_rfs, tm_rfs,
                                       coxo, T, nt, B, D);
  finalize_kernel<<<1, 256, 0, stream>>>(Ra, Rb, scalPart, T, coxo, intra_wsi, intra_ct, (float*)d_out, B);
}

// Round 7
// 103.687 us; speedup vs baseline: 6.8002x; 1.2269x over previous
//
#include <hip/hip_runtime.h>
#include <hip/hip_bf16.h>
#include <math.h>

typedef __attribute__((ext_vector_type(4))) float f32x4;
typedef __attribute__((ext_vector_type(4))) int int4v;

#define NBINS 1000

// direct global -> LDS async copy, 16B per lane; LDS dest = wave-uniform base
__device__ __forceinline__ void gl16(const void* g, void* l) {
  __builtin_amdgcn_global_load_lds(
      (const __attribute__((address_space(1))) unsigned int*)g,
      (__attribute__((address_space(3))) unsigned int*)l, 16, 0, 0);
}

// decode OCP e4m3fn byte -> |value| (sign irrelevant for norms)
__device__ __forceinline__ float fp8mag(unsigned b) {
  const int e = (b >> 3) & 15;
  const int m = b & 7;
  return e ? ldexpf((float)(8 + m), e - 10) : ldexpf((float)m, -9);
}

// ---------------------------------------------------------------------------
// prep: quantize z to fp8 e4m3 and write PANEL-PACKED + BANK-SWIZZLED image:
// panel(tile) = 128 rows x 256 k bytes, as 4 super-chunks (sc=k/64) of
// [row][64B]; row's 64B = 4 slots of 16B, physical slot = kg ^ ((row>>1)&3);
// slot bytes [0..7] = k = sc*64 + kg*8 + 0..7 (even K=32 half),
//            [8..15] = k = sc*64 + 32 + kg*8 + 0..7 (odd half).
// Row norms computed from the QUANTIZED values (self-consistent with MFMA).
// ---------------------------------------------------------------------------
__global__ __launch_bounds__(256)
void prep_kernel(const float* __restrict__ za, const float* __restrict__ zb,
                 float* __restrict__ na, float* __restrict__ nb,
                 unsigned char* __restrict__ zpa, unsigned char* __restrict__ zpb,
                 int B, int D)
{
  const int row = blockIdx.x * 4 + (threadIdx.x >> 6);
  const int lane = threadIdx.x & 63;
  const float* src; float* dst; unsigned char* bd; int r;
  if (row < B) { src = za; dst = na; bd = zpa; r = row; }
  else         { src = zb; dst = nb; bd = zpb; r = row - B; }
  const int pt = r >> 7;
  const int rr = r & 127;
  const int sw = (rr >> 1) & 3;
  const size_t tbase = (size_t)pt * 128 * D;  // bytes
  float s = 0.f;
  for (int c = lane * 4; c < D; c += 256) {
    const f32x4 v = *(const f32x4*)&src[(size_t)r * D + c];
    unsigned u = (unsigned)__builtin_amdgcn_cvt_pk_fp8_f32(v[0], v[1], 0, false);
    u = (unsigned)__builtin_amdgcn_cvt_pk_fp8_f32(v[2], v[3], (int)u, true);
    const int sc = c >> 6;
    const int half = (c >> 5) & 1;
    const int kg = (c >> 3) & 3;
    const int rem = c & 7;  // 0 or 4
    const int slot = kg ^ sw;
    *(unsigned*)&bd[tbase + sc * 8192 + rr * 64 + slot * 16 + half * 8 + rem] = u;
    const float x0 = fp8mag(u & 255), x1 = fp8mag((u >> 8) & 255);
    const float x2 = fp8mag((u >> 16) & 255), x3 = fp8mag(u >> 24);
    s += x0 * x0 + x1 * x1 + x2 * x2 + x3 * x3;
  }
#pragma unroll
  for (int off = 32; off; off >>= 1) s += __shfl_xor(s, off);
  if (lane == 0) dst[r] = s;
}

// ---------------------------------------------------------------------------
// Merged kernel, grid = 512 (2 blocks/CU):
//   blocks 0,1   : Efron Cox losses (integer-time binning)
//   blocks 2..511: persistent dcor blocks, 4-5 consecutive triangular tiles,
//                  flat (tile,sc) pipeline (K=64/step), counted vmcnt + raw
//                  barriers, fp8 MFMA.
// ---------------------------------------------------------------------------
__global__ __launch_bounds__(256, 2)
void dcor_kernel(const unsigned char* __restrict__ zpa,
                 const unsigned char* __restrict__ zpb,
                 const float* __restrict__ na, const float* __restrict__ nb,
                 float* __restrict__ Ra, float* __restrict__ Rb,
                 double* __restrict__ scalPart,
                 const float* __restrict__ r0, const int* __restrict__ e0, const int* __restrict__ t0,
                 const float* __restrict__ r1, const int* __restrict__ e1, const int* __restrict__ t1,
                 float* __restrict__ coxo,
                 int T, int nt, int B, int D)
{
  __shared__ __align__(16) union SU {
    unsigned char g[2][32768];  // [buf][panel p*8192]; p: Ai=0 Aj=1 Bi=2 Bj=3
    struct { float sS[NBINS], sT[NBINS], sDc[NBINS], sc0[NBINS], sc1[NBINS], red[16], red3[48]; } c;
  } u;

  const int tid = threadIdx.x;
  const int bid = blockIdx.x;

  if (bid < 2) {
    // ---------------- Cox path ----------------
    const float* risk = bid ? r1 : r0;
    const int* evt = bid ? e1 : e0;
    const int* tm  = bid ? t1 : t0;
    const int NT = 256;

    float m = -3.0e38f;
    for (int i = tid; i < B; i += NT) m = fmaxf(m, risk[i]);
#pragma unroll
    for (int off = 32; off; off >>= 1) m = fmaxf(m, __shfl_xor(m, off));
    if ((tid & 63) == 0) u.c.red[tid >> 6] = m;
    __syncthreads();
    if (tid == 0) {
      float mm = u.c.red[0];
      for (int wv = 1; wv < 4; ++wv) mm = fmaxf(mm, u.c.red[wv]);
      u.c.red[0] = mm;
    }
    __syncthreads();
    const float maxr = u.c.red[0];

    for (int i = tid; i < NBINS; i += NT) { u.c.sS[i] = 0.f; u.c.sT[i] = 0.f; u.c.sDc[i] = 0.f; }
    __syncthreads();

    float sr = 0.f, nev = 0.f;
    for (int i = tid; i < B; i += NT) {
      const float r = risk[i];
      int t = tm[i];
      t = t < 0 ? 0 : (t >= NBINS ? NBINS - 1 : t);
      const float ex = expf(r - maxr);
      atomicAdd(&u.c.sS[t], ex);
      if (evt[i]) {
        atomicAdd(&u.c.sT[t], ex);
        atomicAdd(&u.c.sDc[t], 1.0f);
        sr += r; nev += 1.0f;
      }
    }
    __syncthreads();

    for (int i = tid; i < NBINS; i += NT) u.c.sc0[i] = u.c.sS[i];
    __syncthreads();
    float* pin = u.c.sc0; float* pout = u.c.sc1;
    for (int off = 1; off < NBINS; off <<= 1) {
      for (int i = tid; i < NBINS; i += NT) {
        float v = pin[i];
        if (i + off < NBINS) v += pin[i + off];
        pout[i] = v;
      }
      __syncthreads();
      float* tmp = pin; pin = pout; pout = tmp;
    }

    float ls = 0.f;
    for (int t = tid; t < NBINS; t += NT) {
      const float d = u.c.sDc[t];
      if (d > 0.f) {
        const float tes = u.c.sT[t];
        const float rs = pin[t];
        for (float l = 0.f; l < d - 0.5f; l += 1.f)
          ls += logf(rs - (l / d) * tes + 1e-12f);
      }
    }

    float v1 = sr, v2 = nev, v3 = ls;
#pragma unroll
    for (int off = 32; off; off >>= 1) {
      v1 += __shfl_xor(v1, off); v2 += __shfl_xor(v2, off); v3 += __shfl_xor(v3, off);
    }
    if ((tid & 63) == 0) { int wv = tid >> 6; u.c.red3[wv] = v1; u.c.red3[16 + wv] = v2; u.c.red3[32 + wv] = v3; }
    __syncthreads();
    if (tid == 0) {
      float SR = 0.f, NEV = 0.f, LS = 0.f;
      for (int wv = 0; wv < 4; ++wv) { SR += u.c.red3[wv]; NEV += u.c.red3[16 + wv]; LS += u.c.red3[32 + wv]; }
      coxo[bid] = -(SR - LS - NEV * maxr) / (NEV + 1e-12f);
    }
    return;
  }

  // ---------------- dcor path ----------------
  const int lane = tid & 63;
  const int w = tid >> 6;
  const int p = bid - 2;  // 0..509

  // XCD-bijective banded block->q map (510 = 6*64 + 2*63)
  const int xcd = p & 7, pos = p >> 3;
  const int q = (xcd < 6 ? xcd * 64 : 384 + (xcd - 6) * 63) + pos;
  const int start = 4 * q + (q + 12) / 13;
  const int cnt = 4 + ((q % 13) == 0 ? 1 : 0);

  // decode start -> (ib0, jb0) in triangular order (jb >= ib)
  const double tn = (double)(2 * nt + 1);
  int ib0 = (int)((tn - sqrt(tn * tn - 8.0 * (double)start)) * 0.5);
  if (ib0 < 0) ib0 = 0;
  if (ib0 > nt - 1) ib0 = nt - 1;
  while (((ib0 + 1) * nt - ((ib0 + 1) * ib0) / 2) <= start) ++ib0;
  while ((ib0 * nt - (ib0 * (ib0 - 1)) / 2) > start) --ib0;
  const int jb0 = ib0 + (start - (ib0 * nt - (ib0 * (ib0 - 1)) / 2));

  // staging geometry: per wave, per panel, 2 gl16 covering rows w*32..w*32+31
  const int gofs = w * 2048 + lane * 16;  // bytes within panel super-chunk
  const int lofs = w * 2048;              // wave-uniform LDS dest offset

  int sib = ib0, sjb = jb0;  // staging tile
  int cib = ib0, cjb = jb0;  // compute tile
  const unsigned char* gAi = zpa + (size_t)sib * 32768;
  const unsigned char* gAj = zpa + (size_t)sjb * 32768;
  const unsigned char* gBi = zpb + (size_t)sib * 32768;
  const unsigned char* gBj = zpb + (size_t)sjb * 32768;

#define STAGE(par_, sc_) do {                                        \
    const size_t co_ = (size_t)(sc_) * 8192 + gofs;                  \
    unsigned char* lb_ = &u.g[par_][lofs];                           \
    gl16(gAi + co_,        lb_);                                     \
    gl16(gAi + co_ + 1024, lb_ + 1024);                              \
    gl16(gAj + co_,        lb_ + 8192);                              \
    gl16(gAj + co_ + 1024, lb_ + 9216);                              \
    gl16(gBi + co_,        lb_ + 16384);                             \
    gl16(gBi + co_ + 1024, lb_ + 17408);                             \
    gl16(gBj + co_,        lb_ + 24576);                             \
    gl16(gBj + co_ + 1024, lb_ + 25600);                             \
  } while (0)

  // fragment geometry
  const int wr = w >> 1, wc = w & 1;
  const int lrow = lane & 15;
  const int kg = lane >> 4;
  const int kgx = kg ^ ((lrow >> 1) & 3);   // swizzled slot (row-dependent part constant per lane)
  const int abase = (wr * 64 + lrow) * 64 + kgx * 16;
  const int bbase = (wc * 64 + lrow) * 64 + kgx * 16;

  union I4L { int4v v; long l[2]; };

  const f32x4 Z4 = {0.f, 0.f, 0.f, 0.f};
  f32x4 accA[4][4], accB[4][4];
#pragma unroll
  for (int m = 0; m < 4; ++m)
#pragma unroll
    for (int n = 0; n < 4; ++n) { accA[m][n] = Z4; accB[m][n] = Z4; }

  const int S = cnt * 4;  // 4 super-chunk steps per tile (K=64 each)
  STAGE(0, 0);
  STAGE(1, 1);

  for (int s = 0; s < S; ++s) {
    const int k = s & 3;
    const int par = s & 1;

    if (s < S - 1) asm volatile("s_waitcnt vmcnt(8)" ::: "memory");
    else           asm volatile("s_waitcnt vmcnt(0)" ::: "memory");
    __builtin_amdgcn_sched_barrier(0);
    __builtin_amdgcn_s_barrier();
    __builtin_amdgcn_sched_barrier(0);

    {
      const unsigned char* lAi = &u.g[par][0];
      const unsigned char* lAj = &u.g[par][8192];
      I4L aA[4], bA[4];
#pragma unroll
      for (int m2 = 0; m2 < 4; ++m2) {
        aA[m2].v = *(const int4v*)&lAi[abase + m2 * 1024];
        bA[m2].v = *(const int4v*)&lAj[bbase + m2 * 1024];
      }
      __builtin_amdgcn_s_setprio(1);
#pragma unroll
      for (int m2 = 0; m2 < 4; ++m2)
#pragma unroll
        for (int n2 = 0; n2 < 4; ++n2) {
          accA[m2][n2] = __builtin_amdgcn_mfma_f32_16x16x32_fp8_fp8(aA[m2].l[0], bA[n2].l[0], accA[m2][n2], 0, 0, 0);
          accA[m2][n2] = __builtin_amdgcn_mfma_f32_16x16x32_fp8_fp8(aA[m2].l[1], bA[n2].l[1], accA[m2][n2], 0, 0, 0);
        }
      __builtin_amdgcn_s_setprio(0);
      const unsigned char* lBi = &u.g[par][16384];
      const unsigned char* lBj = &u.g[par][24576];
      I4L aB[4], bB[4];
#pragma unroll
      for (int m2 = 0; m2 < 4; ++m2) {
        aB[m2].v = *(const int4v*)&lBi[abase + m2 * 1024];
        bB[m2].v = *(const int4v*)&lBj[bbase + m2 * 1024];
      }
      __builtin_amdgcn_s_setprio(1);
#pragma unroll
      for (int m2 = 0; m2 < 4; ++m2)
#pragma unroll
        for (int n2 = 0; n2 < 4; ++n2) {
          accB[m2][n2] = __builtin_amdgcn_mfma_f32_16x16x32_fp8_fp8(aB[m2].l[0], bB[n2].l[0], accB[m2][n2], 0, 0, 0);
          accB[m2][n2] = __builtin_amdgcn_mfma_f32_16x16x32_fp8_fp8(aB[m2].l[1], bB[n2].l[1], accB[m2][n2], 0, 0, 0);
        }
      __builtin_amdgcn_s_setprio(0);
    }

    __builtin_amdgcn_sched_barrier(0);
    __builtin_amdgcn_s_barrier();
    __builtin_amdgcn_sched_barrier(0);

    if (s + 2 < S) {
      const int s2 = s + 2;
      if ((s2 & 3) == 0) {  // s+2 starts a new tile
        if (++sjb == nt) { ++sib; sjb = sib; }
        gAi = zpa + (size_t)sib * 32768;
        gAj = zpa + (size_t)sjb * 32768;
        gBi = zpb + (size_t)sib * 32768;
        gBj = zpb + (size_t)sjb * 32768;
      }
      STAGE(par, s2 & 3);
    }

    if (k == 3) {
      // ---------------- epilogue for tile (cib,cjb) ----------------
      const bool offd = (cjb != cib);
      const float fac = offd ? 2.0f : 1.0f;
      float pab = 0.f, paa = 0.f, pbb = 0.f;
      float rsa[4][4], rsb[4][4];
      float csa[4] = {0.f, 0.f, 0.f, 0.f}, csb[4] = {0.f, 0.f, 0.f, 0.f};
#pragma unroll
      for (int m2 = 0; m2 < 4; ++m2)
#pragma unroll
        for (int r = 0; r < 4; ++r) { rsa[m2][r] = 0.f; rsb[m2][r] = 0.f; }

      const int gi0 = cib * 128 + wr * 64;
      const int gj0 = cjb * 128 + wc * 64;

#pragma unroll
      for (int m2 = 0; m2 < 4; ++m2) {
        const int gr = gi0 + m2 * 16 + kg * 4;
        const f32x4 nai = *(const f32x4*)&na[gr];
        const f32x4 nbi = *(const f32x4*)&nb[gr];
#pragma unroll
        for (int n2 = 0; n2 < 4; ++n2) {
          const int gc = gj0 + n2 * 16 + lrow;
          const float naj = na[gc];
          const float nbj = nb[gc];
          const f32x4 ga = accA[m2][n2];
          const f32x4 gb = accB[m2][n2];
#pragma unroll
          for (int r = 0; r < 4; ++r) {
            const float d2a = fmaxf(nai[r] + naj - 2.0f * ga[r], 1e-8f);
            const float d2b = fmaxf(nbi[r] + nbj - 2.0f * gb[r], 1e-8f);
            const float Da = __builtin_amdgcn_sqrtf(d2a);
            const float Db = __builtin_amdgcn_sqrtf(d2b);
            pab += Da * Db;
            paa += d2a;
            pbb += d2b;
            rsa[m2][r] += Da;
            rsb[m2][r] += Db;
            csa[n2] += Da;
            csb[n2] += Db;
          }
        }
      }

#pragma unroll
      for (int m2 = 0; m2 < 4; ++m2)
#pragma unroll
        for (int r = 0; r < 4; ++r) {
          float va = rsa[m2][r], vb = rsb[m2][r];
          va += __shfl_xor(va, 1); va += __shfl_xor(va, 2); va += __shfl_xor(va, 4); va += __shfl_xor(va, 8);
          vb += __shfl_xor(vb, 1); vb += __shfl_xor(vb, 2); vb += __shfl_xor(vb, 4); vb += __shfl_xor(vb, 8);
          if (lrow == 0) {
            const int gi = gi0 + m2 * 16 + kg * 4 + r;
            atomicAdd(&Ra[gi], va);
            atomicAdd(&Rb[gi], vb);
          }
        }

      if (offd) {
#pragma unroll
        for (int n2 = 0; n2 < 4; ++n2) {
          float va = csa[n2], vb = csb[n2];
          va += __shfl_xor(va, 16); va += __shfl_xor(va, 32);
          vb += __shfl_xor(vb, 16); vb += __shfl_xor(vb, 32);
          if (kg == 0) {
            const int gj = gj0 + n2 * 16 + lrow;
            atomicAdd(&Ra[gj], va);
            atomicAdd(&Rb[gj], vb);
          }
        }
      }

      float q1 = fac * pab, q2 = fac * paa, q3 = fac * pbb;
#pragma unroll
      for (int off = 32; off; off >>= 1) {
        q1 += __shfl_xor(q1, off); q2 += __shfl_xor(q2, off); q3 += __shfl_xor(q3, off);
      }
      if (lane == 0) {  // unique per-(tile,wave) slot
        const int ctile = start + (s >> 2);
        double* sp = scalPart + (size_t)ctile * 12 + w * 3;
        sp[0] = (double)q1; sp[1] = (double)q2; sp[2] = (double)q3;
      }

      if (++cjb == nt) { ++cib; cjb = cib; }
#pragma unroll
      for (int m2 = 0; m2 < 4; ++m2)
#pragma unroll
        for (int n2 = 0; n2 < 4; ++n2) { accA[m2][n2] = Z4; accB[m2][n2] = Z4; }
    }
  }
#undef STAGE
}

// ---------------------------------------------------------------------------
// Final combine (fp64 to survive the ~4-decade cancellation in S terms).
// ---------------------------------------------------------------------------
__global__ __launch_bounds__(256)
void finalize_kernel(const float* __restrict__ Ra, const float* __restrict__ Rb,
                     const double* __restrict__ scalPart, int T,
                     const float* __restrict__ coxo,
                     const float* __restrict__ iw, const float* __restrict__ ic,
                     float* __restrict__ out, int B)
{
  const int tid = threadIdx.x;
  double v[8];
#pragma unroll
  for (int k = 0; k < 8; ++k) v[k] = 0.0;
  for (int i = tid; i < B; i += 256) {
    const double a = Ra[i], b = Rb[i];
    v[0] += a; v[1] += b; v[2] += a * b; v[3] += a * a; v[4] += b * b;
  }
  for (int i = tid; i < T; i += 256) {
    const double* sp = scalPart + (size_t)i * 12;
    v[5] += sp[0] + sp[3] + sp[6] + sp[9];
    v[6] += sp[1] + sp[4] + sp[7] + sp[10];
    v[7] += sp[2] + sp[5] + sp[8] + sp[11];
  }
#pragma unroll
  for (int k = 0; k < 8; ++k)
#pragma unroll
    for (int off = 32; off; off >>= 1) v[k] += __shfl_xor(v[k], off);
  __shared__ double sred[32];
  const int w = tid >> 6;
  if ((tid & 63) == 0) {
#pragma unroll
    for (int k = 0; k < 8; ++k) sred[k * 4 + w] = v[k];
  }
  __syncthreads();
  if (tid == 0) {
    double r[8];
#pragma unroll
    for (int k = 0; k < 8; ++k) r[k] = sred[k * 4] + sred[k * 4 + 1] + sred[k * 4 + 2] + sred[k * 4 + 3];
    const double ta = r[0], tb = r[1], sab = r[2], saa = r[3], sbb = r[4];
    const double Pab = r[5], Paa = r[6], Pbb = r[7];
    const double n = (double)B;
    const double Sab = Pab - (2.0 / n) * sab + ta * tb / (n * n);
    const double Saa = Paa - (2.0 / n) * saa + ta * ta / (n * n);
    const double Sbb = Pbb - (2.0 / n) * sbb + tb * tb / (n * n);
    const double dcov = Sab / (n * n);
    const double va = Saa / (n * n);
    const double vb = Sbb / (n * n);
    const double l_cca = 1.0 - dcov / sqrt(fmax(va * vb, 1e-8));
    const double total = (double)coxo[0] + (double)coxo[1]
                       + (0.1 * l_cca + 0.05 * ((double)iw[0] + (double)ic[0]));
    out[0] = (float)total;
  }
}

// ---------------------------------------------------------------------------
extern "C" void kernel_launch(void* const* d_in, const int* in_sizes, int n_in,
                              void* d_out, int out_size, void* d_ws, size_t ws_size,
                              hipStream_t stream)
{
  (void)n_in; (void)out_size; (void)ws_size;
  const float* risk_os   = (const float*)d_in[0];
  const float* risk_rfs  = (const float*)d_in[1];
  const float* z_ct      = (const float*)d_in[2];
  const float* z_wsi     = (const float*)d_in[3];
  const float* intra_wsi = (const float*)d_in[4];
  const float* intra_ct  = (const float*)d_in[5];
  const int* evt_os  = (const int*)d_in[6];
  const int* tm_os   = (const int*)d_in[7];
  const int* evt_rfs = (const int*)d_in[8];
  const int* tm_rfs  = (const int*)d_in[9];

  const int B = in_sizes[0];        // 8192
  const int D = in_sizes[2] / B;    // 256
  const int nt = B / 128;           // 64
  const int T = nt * (nt + 1) / 2;  // 2080

  // ws layout (float units):
  // [0,B) Ra | [B,2B) Rb | [2B,2B+16) coxo/pad | [2B+16,3B+16) na |
  // [3B+16,4B+16) nb | scalPart (12T doubles = 24T floats) | fp8 packed z
  float* ws = (float*)d_ws;
  float* Ra = ws;
  float* Rb = ws + B;
  float* coxo = ws + 2 * B;
  float* na  = ws + 2 * B + 16;
  float* nbv = ws + 3 * B + 16;
  double* scalPart = (double*)(ws + 4 * B + 16);
  unsigned char* zpa = (unsigned char*)(ws + 4 * B + 16 + 24 * T);
  unsigned char* zpb = zpa + (size_t)B * D;

  (void)hipMemsetAsync(d_ws, 0, (size_t)(2 * B) * sizeof(float), stream);

  prep_kernel<<<(2 * B) / 4, 256, 0, stream>>>(z_ct, z_wsi, na, nbv, zpa, zpb, B, D);
  dcor_kernel<<<512, 256, 0, stream>>>(zpa, zpb, na, nbv, Ra, Rb, scalPart,
                                       risk_os, evt_os, tm_os, risk_rfs, evt_rfs, tm_rfs,
                                       coxo, T, nt, B, D);
  finalize_kernel<<<1, 256, 0, stream>>>(Ra, Rb, scalPart, T, coxo, intra_wsi, intra_ct, (float*)d_out, B);
}